// Round 1
// baseline (1135.021 us; speedup 1.0000x reference)
//
#include <hip/hip_runtime.h>
#include <hip/hip_bf16.h>

#define G 160
#define GM1 159
#define KD 128   // 16 k * 8 d complex channels
#define TWO_PI_F 6.28318530717958647692f

// ---------------------------------------------------------------------------
// W table: Ctab[a*160+b] = cos(2*pi*a*b/160)/160, Stab = sin(...)/160
// (symmetric, used for both left and right DFT multiplies; ifft sign is +)
// ---------------------------------------------------------------------------
__global__ void k_init_w(float* __restrict__ Ctab, float* __restrict__ Stab) {
    int idx = blockIdx.x * blockDim.x + threadIdx.x;
    if (idx >= G * G) return;
    int a = idx / G, b = idx % G;
    int m = (a * b) % G;                       // exact integer phase reduction
    float th = (float)m * (TWO_PI_F / (float)G);
    float s, c;
    __sincosf(th, &s, &c);
    Ctab[idx] = c * (1.0f / (float)G);
    Stab[idx] = s * (1.0f / (float)G);
}

// ---------------------------------------------------------------------------
// Stage 1: B[(k,d,p)][l] = alpha * sum_q A[k,d,p,q] * W[l,q]   (complex)
// A is read with per-table strides (sk,sd,sp,sq). M=20480, N=160, K=160.
// Block: 256 threads, 32x32 tile, 2x2 complex outputs per thread.
// ---------------------------------------------------------------------------
__global__ __launch_bounds__(256) void k_stage1(
    const float* __restrict__ Are, const float* __restrict__ Aim,
    const float* __restrict__ alpha_params,
    const float* __restrict__ Ctab, const float* __restrict__ Stab,
    float2* __restrict__ B,
    int sk, int sd, int sp, int sq)
{
    __shared__ float As_re[32][17], As_im[32][17];
    __shared__ float Wc_s[16][33], Ws_s[16][33];

    int tid = threadIdx.x;
    int m0 = blockIdx.x * 32;
    int l0 = blockIdx.y * 32;

    float ap = alpha_params[0];
    float bxv = 10.0f * ap;
    float alpha = (bxv > 1.0f) ? ap : log1pf(expf(fminf(bxv, 1.0f))) * 0.1f;

    float accr[2][2] = {{0.f,0.f},{0.f,0.f}};
    float acci[2][2] = {{0.f,0.f},{0.f,0.f}};
    int tx = tid & 15, ty = tid >> 4;

    int alr = tid >> 4, alc = tid & 15;   // A tile loader: 16 rows x 16 cols
    int wlr = tid >> 5, wlc = tid & 31;   // W tile loader: 8 rows x 32 cols

    for (int q0 = 0; q0 < G; q0 += 16) {
        for (int rr = alr; rr < 32; rr += 16) {
            int m = m0 + rr;
            int k = m / 1280;
            int r = m - k * 1280;
            int d = r / 160;
            int p = r - d * 160;
            int off = k * sk + d * sd + p * sp + (q0 + alc) * sq;
            As_re[rr][alc] = Are[off];
            As_im[rr][alc] = Aim[off];
        }
        for (int rr = wlr; rr < 16; rr += 8) {
            int q = q0 + rr;
            Wc_s[rr][wlc] = Ctab[q * G + l0 + wlc];
            Ws_s[rr][wlc] = Stab[q * G + l0 + wlc];
        }
        __syncthreads();
        #pragma unroll
        for (int kk = 0; kk < 16; kk++) {
            float ar0 = As_re[ty*2+0][kk], ai0 = As_im[ty*2+0][kk];
            float ar1 = As_re[ty*2+1][kk], ai1 = As_im[ty*2+1][kk];
            float c0 = Wc_s[kk][tx*2+0], s0 = Ws_s[kk][tx*2+0];
            float c1 = Wc_s[kk][tx*2+1], s1 = Ws_s[kk][tx*2+1];
            accr[0][0] += ar0*c0 - ai0*s0;  acci[0][0] += ar0*s0 + ai0*c0;
            accr[0][1] += ar0*c1 - ai0*s1;  acci[0][1] += ar0*s1 + ai0*c1;
            accr[1][0] += ar1*c0 - ai1*s0;  acci[1][0] += ar1*s0 + ai1*c0;
            accr[1][1] += ar1*c1 - ai1*s1;  acci[1][1] += ar1*s1 + ai1*c1;
        }
        __syncthreads();
    }
    #pragma unroll
    for (int mi = 0; mi < 2; mi++)
        #pragma unroll
        for (int li = 0; li < 2; li++) {
            int m = m0 + ty*2 + mi;
            int l = l0 + tx*2 + li;
            B[(size_t)m * G + l] = make_float2(alpha * accr[mi][li],
                                               alpha * acci[mi][li]);
        }
}

// ---------------------------------------------------------------------------
// Stage 2: T[j][l][kd] = sum_p W[j,p] * B[(kd,p)][l]   (complex)
// Output layout channel-last: T[(j*160+l)*128 + kd] as float2 (re,im).
// grid (128 kd, 5 j-tiles, 5 l-tiles); block 256, 32x32 tile, 2x2/thread.
// ---------------------------------------------------------------------------
__global__ __launch_bounds__(256) void k_stage2(
    const float2* __restrict__ B,
    const float* __restrict__ Ctab, const float* __restrict__ Stab,
    float2* __restrict__ T)
{
    __shared__ float Wc_s[32][17], Ws_s[32][17];
    __shared__ float Br_s[16][33], Bi_s[16][33];

    int tid = threadIdx.x;
    int kd = blockIdx.x;
    int j0 = blockIdx.y * 32;
    int l0 = blockIdx.z * 32;

    const float2* Bkd = B + (size_t)kd * (G * G);

    float accr[2][2] = {{0.f,0.f},{0.f,0.f}};
    float acci[2][2] = {{0.f,0.f},{0.f,0.f}};
    int tx = tid & 15, ty = tid >> 4;

    int wlr = tid >> 4, wlc = tid & 15;   // W tile: 32 rows x 16 cols
    int blr = tid >> 5, blc = tid & 31;   // B tile: 16 rows x 32 cols

    for (int p0 = 0; p0 < G; p0 += 16) {
        for (int rr = wlr; rr < 32; rr += 16) {
            Wc_s[rr][wlc] = Ctab[(j0 + rr) * G + p0 + wlc];
            Ws_s[rr][wlc] = Stab[(j0 + rr) * G + p0 + wlc];
        }
        for (int rr = blr; rr < 16; rr += 8) {
            float2 b = Bkd[(size_t)(p0 + rr) * G + l0 + blc];
            Br_s[rr][blc] = b.x;
            Bi_s[rr][blc] = b.y;
        }
        __syncthreads();
        #pragma unroll
        for (int kk = 0; kk < 16; kk++) {
            float c0 = Wc_s[ty*2+0][kk], s0 = Ws_s[ty*2+0][kk];
            float c1 = Wc_s[ty*2+1][kk], s1 = Ws_s[ty*2+1][kk];
            float br0 = Br_s[kk][tx*2+0], bi0 = Bi_s[kk][tx*2+0];
            float br1 = Br_s[kk][tx*2+1], bi1 = Bi_s[kk][tx*2+1];
            accr[0][0] += c0*br0 - s0*bi0;  acci[0][0] += c0*bi0 + s0*br0;
            accr[0][1] += c0*br1 - s0*bi1;  acci[0][1] += c0*bi1 + s0*br1;
            accr[1][0] += c1*br0 - s1*bi0;  acci[1][0] += c1*bi0 + s1*br0;
            accr[1][1] += c1*br1 - s1*bi1;  acci[1][1] += c1*bi1 + s1*br1;
        }
        __syncthreads();
    }
    #pragma unroll
    for (int ji = 0; ji < 2; ji++)
        #pragma unroll
        for (int li = 0; li < 2; li++) {
            int j = j0 + ty*2 + ji;
            int l = l0 + tx*2 + li;
            T[(size_t)(j * G + l) * KD + kd] =
                make_float2(accr[ji][li], acci[ji][li]);
        }
}

// ---------------------------------------------------------------------------
// Sampler: half-block (128 lanes) per point; lane = (k,d) channel.
// Per plane: 4 bilinear corners (coalesced 1KB/cell float2 reads),
// then re*cos - im*sin with octave freq, shfl_xor reduce over d.
// ---------------------------------------------------------------------------
__device__ __forceinline__ float plane_eval(const float2* __restrict__ T,
                                            float gy, float gx, float fcoord,
                                            float fd, float scale, int lane)
{
    float iy = (gy + 1.0f) * 0.5f * (float)GM1;
    float ix = (gx + 1.0f) * 0.5f * (float)GM1;
    float iy0f = floorf(iy), ix0f = floorf(ix);
    float wy = iy - iy0f, wx = ix - ix0f;
    int iy0 = (int)iy0f, ix0 = (int)ix0f;
    int iy1 = min(iy0 + 1, GM1), ix1 = min(ix0 + 1, GM1);
    iy0 = max(min(iy0, GM1), 0);  ix0 = max(min(ix0, GM1), 0);
    iy1 = max(iy1, 0);            ix1 = max(ix1, 0);

    float2 v00 = T[(size_t)(iy0 * G + ix0) * KD + lane];
    float2 v01 = T[(size_t)(iy0 * G + ix1) * KD + lane];
    float2 v10 = T[(size_t)(iy1 * G + ix0) * KD + lane];
    float2 v11 = T[(size_t)(iy1 * G + ix1) * KD + lane];

    float w00 = (1.0f - wx) * (1.0f - wy);
    float w01 = wx * (1.0f - wy);
    float w10 = (1.0f - wx) * wy;
    float w11 = wx * wy;
    float re = v00.x*w00 + v01.x*w01 + v10.x*w10 + v11.x*w11;
    float im = v00.y*w00 + v01.y*w01 + v10.y*w10 + v11.y*w11;

    float sv, cv;
    __sincosf(TWO_PI_F * fcoord * fd, &sv, &cv);
    return (re * cv - im * sv) * scale;
}

__global__ __launch_bounds__(256) void k_sample(
    const float* __restrict__ xyz, const float* __restrict__ bound,
    const float2* __restrict__ Tu, const float2* __restrict__ Tv,
    const float2* __restrict__ Tw,
    float* __restrict__ out, int N)
{
    int half = threadIdx.x >> 7;
    int lane = threadIdx.x & 127;
    int n = blockIdx.x * 2 + half;
    if (n >= N) return;
    int k = lane >> 3, d = lane & 7;

    float invb = 1.0f / bound[0];
    float x = xyz[3*n+0] * invb;
    float y = xyz[3*n+1] * invb;
    float z = xyz[3*n+2] * invb;
    float xx = (x + 1.0f) * 0.5f;
    float yy = (y + 1.0f) * 0.5f;
    float zz = (z + 1.0f) * 0.5f;

    float fd = (d == 0) ? 0.0f : (float)(1 << (d - 1));   // 0,1,2,4,8,16,32,64
    float scale = (d == 0) ? 1.0f : 2.0f;

    float acc = 0.0f;
    acc += plane_eval(Tu, y, z, xx, fd, scale, lane);  // u: (gy,gx)=(y,z), freq x
    acc += plane_eval(Tv, x, z, yy, fd, scale, lane);  // v: (gy,gx)=(x,z), freq y
    acc += plane_eval(Tw, y, x, zz, fd, scale, lane);  // w: (gy,gx)=(y,x), freq z

    acc += __shfl_xor(acc, 1);
    acc += __shfl_xor(acc, 2);
    acc += __shfl_xor(acc, 4);
    if (d == 0) out[n * 16 + k] = acc;
}

// ---------------------------------------------------------------------------
extern "C" void kernel_launch(void* const* d_in, const int* in_sizes, int n_in,
                              void* d_out, int out_size, void* d_ws, size_t ws_size,
                              hipStream_t stream) {
    const float* xyz          = (const float*)d_in[0];
    const float* bound        = (const float*)d_in[1];
    const float* alpha_params = (const float*)d_in[2];
    const float* Pu_re = (const float*)d_in[3];
    const float* Pu_im = (const float*)d_in[4];
    const float* Pv_re = (const float*)d_in[5];
    const float* Pv_im = (const float*)d_in[6];
    const float* Pw_re = (const float*)d_in[7];
    const float* Pw_im = (const float*)d_in[8];
    float* out = (float*)d_out;
    int N = in_sizes[0] / 3;

    // workspace layout (floats): Ctab 25600 | Stab 25600 | B 6.5536M | Tu|Tv|Tw
    float* ws   = (float*)d_ws;
    float* Ctab = ws;
    float* Stab = ws + 25600;
    float2* B   = (float2*)(ws + 51200);
    float2* Tu  = (float2*)(ws + 51200 + 6553600);
    float2* Tv  = Tu + (size_t)G * G * KD;   // 3,276,800 float2 per table
    float2* Tw  = Tv + (size_t)G * G * KD;

    k_init_w<<<(G * G + 255) / 256, 256, 0, stream>>>(Ctab, Stab);

    dim3 g1(640, 5), g2(128, 5, 5);
    // Pu: (1,16,8,160,160), ifft axes (3,4); table rows j=y (axis3), cols l=z (axis4)
    k_stage1<<<g1, 256, 0, stream>>>(Pu_re, Pu_im, alpha_params, Ctab, Stab, B,
                                     204800, 25600, 160, 1);
    k_stage2<<<g2, 256, 0, stream>>>(B, Ctab, Stab, Tu);
    // Pv: (1,16,160,8,160), ifft axes (2,4); rows j=x (axis2), cols l=z (axis4)
    k_stage1<<<g1, 256, 0, stream>>>(Pv_re, Pv_im, alpha_params, Ctab, Stab, B,
                                     204800, 160, 1280, 1);
    k_stage2<<<g2, 256, 0, stream>>>(B, Ctab, Stab, Tv);
    // Pw: (1,16,160,160,8), ifft axes (2,3); rows j=y (axis3), cols l=x (axis2)
    k_stage1<<<g1, 256, 0, stream>>>(Pw_re, Pw_im, alpha_params, Ctab, Stab, B,
                                     204800, 1, 8, 1280);
    k_stage2<<<g2, 256, 0, stream>>>(B, Ctab, Stab, Tw);

    k_sample<<<(N + 1) / 2, 256, 0, stream>>>(xyz, bound, Tu, Tv, Tw, out, N);
}

// Round 2
// 553.520 us; speedup vs baseline: 2.0506x; 2.0506x over previous
//
#include <hip/hip_runtime.h>
#include <hip/hip_bf16.h>

#define G 160
#define GM1 159
#define KD 128   // 16 k * 8 d complex channels
#define KP 320   // doubled K (re/im interleaved)
#define TWO_PI_F 6.28318530717958647692f

typedef __attribute__((ext_vector_type(8))) short bf16x8;   // 4 VGPRs, 8 bf16
typedef __attribute__((ext_vector_type(4))) float f32x4;

__device__ __forceinline__ unsigned short f2bf(float x) {
    unsigned u = __float_as_uint(x);
    unsigned r = (u + 0x7FFFu + ((u >> 16) & 1u)) >> 16;   // RNE
    return (unsigned short)r;
}
__device__ __forceinline__ float bf2f(unsigned h) {
    return __uint_as_float(h << 16);
}

// ---------------------------------------------------------------------------
// W2 tables, bf16, fragment-friendly layout [row r][k'] with k' contiguous:
//   k'=2q:   Wre = cos(2*pi*r*q/160)/160,  Wim = sin(...)/160
//   k'=2q+1: Wre = -sin(...)/160,          Wim = cos(...)/160
// W symmetric -> same table serves stage1 (B-operand, row=l) and
// stage2 (A-operand, row=j).
// ---------------------------------------------------------------------------
__global__ void k_init_w(unsigned short* __restrict__ Wre,
                         unsigned short* __restrict__ Wim) {
    int idx = blockIdx.x * blockDim.x + threadIdx.x;
    if (idx >= G * KP) return;
    int r = idx / KP, kp = idx - r * KP;
    int q = kp >> 1;
    int m = (r * q) % G;                    // exact integer phase reduction
    float th = (float)m * (TWO_PI_F / (float)G);
    float s, c;
    __sincosf(th, &s, &c);
    c *= (1.0f / (float)G);
    s *= (1.0f / (float)G);
    float vr, vi;
    if ((kp & 1) == 0) { vr = c;  vi = s; }
    else               { vr = -s; vi = c; }
    Wre[idx] = f2bf(vr);
    Wim[idx] = f2bf(vi);
}

// ---------------------------------------------------------------------------
// Stage 1 (MFMA): B[m][l] = alpha * sum_q A[m][q]*W[l][q]  (complex)
// m=(k,d,p) in [0,20480), l in [0,160). Block: 256 thr = 4 waves, m-tile 64,
// full l=160 (10 l-tiles * 2 outputs = 20 acc frags/wave).
// A tile staged in LDS in MFMA A-fragment order (lane-linear ds_read_b128).
// ---------------------------------------------------------------------------
__global__ __launch_bounds__(256) void k_stage1(
    const float* __restrict__ Are, const float* __restrict__ Aim,
    const float* __restrict__ alpha_params,
    const unsigned short* __restrict__ Wre,
    const unsigned short* __restrict__ Wim,
    float2* __restrict__ B,
    int sk, int sd, int sp, int sq, int qfast)
{
    __shared__ __align__(16) unsigned int s1[10240];   // 40 KB frag stream

    int tid = threadIdx.x;
    int m0b = blockIdx.x * 64;

    // ---- load A tile (64 m-rows x 160 complex q), fp32->bf16, frag order ----
    for (int it = 0; it < 40; it++) {
        int idx = it * 256 + tid;
        int r, q;
        if (qfast) { r = idx / 160; q = idx - r * 160; }   // lanes walk q (sq==1)
        else       { q = idx >> 6;  r = idx & 63; }        // lanes walk r (small sp)
        int m = m0b + r;
        int k = m / 1280; int rm = m - k * 1280;
        int d = rm / 160; int p = rm - d * 160;
        size_t off = (size_t)k * sk + (size_t)d * sd + (size_t)p * sp + (size_t)q * sq;
        float ar = Are[off], ai = Aim[off];
        // k'=2q: t = k'>>5, g = (k'>>3)&3, j = k'&7 (pair j, j+1)
        int t = q >> 4, g = (q >> 2) & 3, j2 = q & 3;
        int w = r >> 4, mrow = r & 15;
        int h = ((w * 10 + t) * 64 + g * 16 + mrow) * 8 + 2 * j2;
        s1[h >> 1] = ((unsigned)f2bf(ai) << 16) | (unsigned)f2bf(ar);
    }
    __syncthreads();

    float ap = alpha_params[0];
    float bx = 10.0f * ap;
    float alpha = (bx > 1.0f) ? ap : log1pf(expf(fminf(bx, 1.0f))) * 0.1f;

    int w = tid >> 6, lane = tid & 63;
    int col = lane & 15, g4 = lane >> 4;

    f32x4 accr[10], acci[10];
    #pragma unroll
    for (int i = 0; i < 10; i++) { accr[i] = (f32x4)(0.0f); acci[i] = (f32x4)(0.0f); }

    for (int t = 0; t < 10; t++) {
        bf16x8 af = *reinterpret_cast<bf16x8*>(&s1[((w * 10 + t) * 64 + lane) * 4]);
        #pragma unroll
        for (int lt = 0; lt < 10; lt++) {
            bf16x8 br = *reinterpret_cast<const bf16x8*>(
                &Wre[(lt * 16 + col) * KP + t * 32 + g4 * 8]);
            bf16x8 bi = *reinterpret_cast<const bf16x8*>(
                &Wim[(lt * 16 + col) * KP + t * 32 + g4 * 8]);
            accr[lt] = __builtin_amdgcn_mfma_f32_16x16x32_bf16(af, br, accr[lt], 0, 0, 0);
            acci[lt] = __builtin_amdgcn_mfma_f32_16x16x32_bf16(af, bi, acci[lt], 0, 0, 0);
        }
    }

    #pragma unroll
    for (int lt = 0; lt < 10; lt++)
        #pragma unroll
        for (int reg = 0; reg < 4; reg++) {
            int m = m0b + w * 16 + g4 * 4 + reg;   // C row = (lane>>4)*4+reg
            int l = lt * 16 + col;                 // C col = lane&15
            B[(size_t)m * G + l] = make_float2(alpha * accr[lt][reg],
                                               alpha * acci[lt][reg]);
        }
}

// ---------------------------------------------------------------------------
// Stage 2 (MFMA): T[j][l][kd] = sum_p W[j][p]*B[kd][p][l]  (complex)
// Block: 640 thr = 10 waves (wave w -> j-tile 16w), one kd, one 16-wide
// l-tile. B column-tile staged in LDS in B-fragment order (shared by all
// waves -> broadcast reads). Output packed bf16 (re,im).
// ---------------------------------------------------------------------------
__global__ __launch_bounds__(640) void k_stage2(
    const float2* __restrict__ B,
    const unsigned short* __restrict__ Wre,
    const unsigned short* __restrict__ Wim,
    unsigned int* __restrict__ T)
{
    __shared__ __align__(16) unsigned int s2[2560];    // 10 KB frag stream

    int tid = threadIdx.x;
    int kd = blockIdx.x;
    int l0 = blockIdx.y * 16;
    const float2* Bkd = B + (size_t)kd * (G * G);

    for (int it = 0; it < 4; it++) {
        int idx = it * 640 + tid;
        int p = idx >> 4, l = idx & 15;
        float2 b = Bkd[(size_t)p * G + l0 + l];
        int t = p >> 4, g = (p >> 2) & 3, j2 = p & 3;
        int h = (t * 64 + g * 16 + l) * 8 + 2 * j2;
        s2[h >> 1] = ((unsigned)f2bf(b.y) << 16) | (unsigned)f2bf(b.x);
    }
    __syncthreads();

    int w = tid >> 6, lane = tid & 63;
    int col = lane & 15, g4 = lane >> 4;

    f32x4 tr = (f32x4)(0.0f), ti = (f32x4)(0.0f);
    for (int t = 0; t < 10; t++) {
        bf16x8 bfrag = *reinterpret_cast<bf16x8*>(&s2[(t * 64 + lane) * 4]);
        bf16x8 wr = *reinterpret_cast<const bf16x8*>(
            &Wre[(w * 16 + col) * KP + t * 32 + g4 * 8]);
        bf16x8 wi = *reinterpret_cast<const bf16x8*>(
            &Wim[(w * 16 + col) * KP + t * 32 + g4 * 8]);
        tr = __builtin_amdgcn_mfma_f32_16x16x32_bf16(wr, bfrag, tr, 0, 0, 0);
        ti = __builtin_amdgcn_mfma_f32_16x16x32_bf16(wi, bfrag, ti, 0, 0, 0);
    }

    #pragma unroll
    for (int reg = 0; reg < 4; reg++) {
        int j = w * 16 + g4 * 4 + reg;
        int l = l0 + col;
        T[((size_t)j * G + l) * KD + kd] =
            ((unsigned)f2bf(ti[reg]) << 16) | (unsigned)f2bf(tr[reg]);
    }
}

// ---------------------------------------------------------------------------
// Sampler: half-block (128 lanes) per point; lane = (k,d) channel.
// Tables are packed bf16 (re in low half, im in high half) -> 4B/lane/corner.
// ---------------------------------------------------------------------------
__device__ __forceinline__ float plane_eval(const unsigned int* __restrict__ T,
                                            float gy, float gx, float fcoord,
                                            float fd, float scale, int lane)
{
    float iy = (gy + 1.0f) * 0.5f * (float)GM1;
    float ix = (gx + 1.0f) * 0.5f * (float)GM1;
    float iy0f = floorf(iy), ix0f = floorf(ix);
    float wy = iy - iy0f, wx = ix - ix0f;
    int iy0 = (int)iy0f, ix0 = (int)ix0f;
    int iy1 = min(iy0 + 1, GM1), ix1 = min(ix0 + 1, GM1);
    iy0 = max(min(iy0, GM1), 0);  ix0 = max(min(ix0, GM1), 0);
    iy1 = max(iy1, 0);            ix1 = max(ix1, 0);

    unsigned v00 = T[(size_t)(iy0 * G + ix0) * KD + lane];
    unsigned v01 = T[(size_t)(iy0 * G + ix1) * KD + lane];
    unsigned v10 = T[(size_t)(iy1 * G + ix0) * KD + lane];
    unsigned v11 = T[(size_t)(iy1 * G + ix1) * KD + lane];

    float w00 = (1.0f - wx) * (1.0f - wy);
    float w01 = wx * (1.0f - wy);
    float w10 = (1.0f - wx) * wy;
    float w11 = wx * wy;
    float re = bf2f(v00 & 0xffffu) * w00 + bf2f(v01 & 0xffffu) * w01
             + bf2f(v10 & 0xffffu) * w10 + bf2f(v11 & 0xffffu) * w11;
    float im = bf2f(v00 >> 16) * w00 + bf2f(v01 >> 16) * w01
             + bf2f(v10 >> 16) * w10 + bf2f(v11 >> 16) * w11;

    float sv, cv;
    __sincosf(TWO_PI_F * fcoord * fd, &sv, &cv);
    return (re * cv - im * sv) * scale;
}

__global__ __launch_bounds__(256) void k_sample(
    const float* __restrict__ xyz, const float* __restrict__ bound,
    const unsigned int* __restrict__ Tu, const unsigned int* __restrict__ Tv,
    const unsigned int* __restrict__ Tw,
    float* __restrict__ out, int N)
{
    int half = threadIdx.x >> 7;
    int lane = threadIdx.x & 127;
    int n = blockIdx.x * 2 + half;
    if (n >= N) return;
    int k = lane >> 3, d = lane & 7;

    float invb = 1.0f / bound[0];
    float x = xyz[3 * n + 0] * invb;
    float y = xyz[3 * n + 1] * invb;
    float z = xyz[3 * n + 2] * invb;
    float xx = (x + 1.0f) * 0.5f;
    float yy = (y + 1.0f) * 0.5f;
    float zz = (z + 1.0f) * 0.5f;

    float fd = (d == 0) ? 0.0f : (float)(1 << (d - 1));   // 0,1,2,4,8,16,32,64
    float scale = (d == 0) ? 1.0f : 2.0f;

    float acc = 0.0f;
    acc += plane_eval(Tu, y, z, xx, fd, scale, lane);  // u: (gy,gx)=(y,z), freq x
    acc += plane_eval(Tv, x, z, yy, fd, scale, lane);  // v: (gy,gx)=(x,z), freq y
    acc += plane_eval(Tw, y, x, zz, fd, scale, lane);  // w: (gy,gx)=(y,x), freq z

    acc += __shfl_xor(acc, 1);
    acc += __shfl_xor(acc, 2);
    acc += __shfl_xor(acc, 4);
    if (d == 0) out[n * 16 + k] = acc;
}

// ---------------------------------------------------------------------------
extern "C" void kernel_launch(void* const* d_in, const int* in_sizes, int n_in,
                              void* d_out, int out_size, void* d_ws, size_t ws_size,
                              hipStream_t stream) {
    const float* xyz          = (const float*)d_in[0];
    const float* bound        = (const float*)d_in[1];
    const float* alpha_params = (const float*)d_in[2];
    const float* Pu_re = (const float*)d_in[3];
    const float* Pu_im = (const float*)d_in[4];
    const float* Pv_re = (const float*)d_in[5];
    const float* Pv_im = (const float*)d_in[6];
    const float* Pw_re = (const float*)d_in[7];
    const float* Pw_im = (const float*)d_in[8];
    float* out = (float*)d_out;
    int N = in_sizes[0] / 3;

    // workspace: Wre 100KB | Wim 100KB | B 25.6MB fp32 | Tu|Tv|Tw 12.5MB bf16
    char* ws = (char*)d_ws;
    unsigned short* Wre = (unsigned short*)(ws);
    unsigned short* Wim = (unsigned short*)(ws + 102400);
    float2*         B   = (float2*)(ws + 204800);
    unsigned int*   Tu  = (unsigned int*)(ws + 204800 + 26214400);
    unsigned int*   Tv  = Tu + (size_t)G * G * KD;
    unsigned int*   Tw  = Tv + (size_t)G * G * KD;

    k_init_w<<<(G * KP + 255) / 256, 256, 0, stream>>>(Wre, Wim);

    dim3 g2(128, 10);
    // Pu: (1,16,8,160,160)  strides k:204800 d:25600 p(y):160   q(z):1    -> qfast
    k_stage1<<<320, 256, 0, stream>>>(Pu_re, Pu_im, alpha_params, Wre, Wim, B,
                                      204800, 25600, 160, 1, 1);
    k_stage2<<<g2, 640, 0, stream>>>(B, Wre, Wim, Tu);
    // Pv: (1,16,160,8,160)  strides k:204800 d:160   p(x):1280  q(z):1    -> qfast
    k_stage1<<<320, 256, 0, stream>>>(Pv_re, Pv_im, alpha_params, Wre, Wim, B,
                                      204800, 160, 1280, 1, 1);
    k_stage2<<<g2, 640, 0, stream>>>(B, Wre, Wim, Tv);
    // Pw: (1,16,160,160,8)  strides k:204800 d:1     p(y):8     q(x):1280 -> rfast
    k_stage1<<<320, 256, 0, stream>>>(Pw_re, Pw_im, alpha_params, Wre, Wim, B,
                                      204800, 1, 8, 1280, 0);
    k_stage2<<<g2, 640, 0, stream>>>(B, Wre, Wim, Tw);

    k_sample<<<(N + 1) / 2, 256, 0, stream>>>(xyz, bound, Tu, Tv, Tw, out, N);
}

// Round 3
// 469.912 us; speedup vs baseline: 2.4154x; 1.1779x over previous
//
#include <hip/hip_runtime.h>
#include <hip/hip_bf16.h>

#define G 160
#define GM1 159
#define KD 128   // 16 k * 8 d complex channels
#define KP 320   // doubled K (re/im interleaved)
#define TWO_PI_F 6.28318530717958647692f

typedef __attribute__((ext_vector_type(8))) short bf16x8;   // 4 VGPRs, 8 bf16
typedef __attribute__((ext_vector_type(4))) float f32x4;

__device__ __forceinline__ unsigned short f2bf(float x) {
    unsigned u = __float_as_uint(x);
    unsigned r = (u + 0x7FFFu + ((u >> 16) & 1u)) >> 16;   // RNE (init path only)
    return (unsigned short)r;
}
__device__ __forceinline__ unsigned int packbf(float re, float im) {
    union { __hip_bfloat162 h; unsigned int u; } cv;
    cv.h = __float22bfloat162_rn(make_float2(re, im));      // v_cvt_pk_bf16_f32
    return cv.u;
}
__device__ __forceinline__ float bfl(unsigned u) { return __uint_as_float(u << 16); }
__device__ __forceinline__ float bfh(unsigned u) { return __uint_as_float(u & 0xffff0000u); }

// ---------------------------------------------------------------------------
// W tables, bf16, fragment-layout [row r][k'] (k'=2q interleaved):
//   k'=2q: (c, s)/160 ; k'=2q+1: (-s, c)/160  -> complex mult via doubled K.
// ---------------------------------------------------------------------------
__global__ void k_init_w(unsigned short* __restrict__ Wre,
                         unsigned short* __restrict__ Wim) {
    int idx = blockIdx.x * blockDim.x + threadIdx.x;
    if (idx >= G * KP) return;
    int r = idx / KP, kp = idx - r * KP;
    int q = kp >> 1;
    int m = (r * q) % G;
    float th = (float)m * (TWO_PI_F / (float)G);
    float s, c;
    __sincosf(th, &s, &c);
    c *= (1.0f / (float)G);
    s *= (1.0f / (float)G);
    float vr, vi;
    if ((kp & 1) == 0) { vr = c;  vi = s; }
    else               { vr = -s; vi = c; }
    Wre[idx] = f2bf(vr);
    Wim[idx] = f2bf(vi);
}

// ---------------------------------------------------------------------------
// Stage 1 (MFMA, no LDS): B[m=(kd,p)][l] = alpha * sum_q A[..]*W[l][q]
// 4 waves/block, wave = 16 m-rows, A-fragments loaded direct from global.
// wmode 0: q contiguous (Pu/Pv), float4 loads. wmode 1 (Pw): tile=(k,8d,8p),
// d is the unit-stride axis so row-direction reads are contiguous.
// B output packed bf16 (im<<16|re).
// ---------------------------------------------------------------------------
__global__ __launch_bounds__(256) void k_stage1(
    const float* __restrict__ Are, const float* __restrict__ Aim,
    const float* __restrict__ alpha_params,
    const unsigned short* __restrict__ Wre,
    const unsigned short* __restrict__ Wim,
    unsigned int* __restrict__ Bb,
    int sk, int sd, int sp, int sq, int wmode)
{
    int tid = threadIdx.x;
    int w = tid >> 6, lane = tid & 63;
    int col = lane & 15, g4 = lane >> 4;

    size_t abase;
    {
        int r = w * 16 + col;            // A-frag row within 64-row tile
        int k, d, p;
        if (wmode == 0) {
            int m = blockIdx.x * 64 + r;
            k = m / 1280; int rm = m - k * 1280;
            d = rm / 160; p = rm - d * 160;
        } else {
            k = blockIdx.x / 20; int pt = blockIdx.x - k * 20;
            d = r & 7; p = pt * 8 + (r >> 3);
        }
        abase = (size_t)k * sk + (size_t)d * sd + (size_t)p * sp;
    }

    float ap = alpha_params[0];
    float bx = 10.0f * ap;
    float alpha = (bx > 1.0f) ? ap : log1pf(expf(fminf(bx, 1.0f))) * 0.1f;

    f32x4 accr[10], acci[10];
    #pragma unroll
    for (int i = 0; i < 10; i++) { accr[i] = (f32x4)(0.f); acci[i] = (f32x4)(0.f); }

    #pragma unroll 2
    for (int t = 0; t < 10; t++) {
        unsigned int afu[4];
        if (wmode == 0) {
            float4 vr = *(const float4*)(Are + abase + t * 16 + g4 * 4);
            float4 vi = *(const float4*)(Aim + abase + t * 16 + g4 * 4);
            afu[0] = packbf(vr.x, vi.x); afu[1] = packbf(vr.y, vi.y);
            afu[2] = packbf(vr.z, vi.z); afu[3] = packbf(vr.w, vi.w);
        } else {
            #pragma unroll
            for (int j2 = 0; j2 < 4; j2++) {
                size_t o = abase + (size_t)(t * 16 + g4 * 4 + j2) * sq;
                afu[j2] = packbf(Are[o], Aim[o]);
            }
        }
        union { unsigned int u[4]; bf16x8 v; } cv;
        cv.u[0] = afu[0]; cv.u[1] = afu[1]; cv.u[2] = afu[2]; cv.u[3] = afu[3];
        bf16x8 af = cv.v;
        #pragma unroll
        for (int lt = 0; lt < 10; lt++) {
            bf16x8 br = *(const bf16x8*)&Wre[(lt * 16 + col) * KP + t * 32 + g4 * 8];
            bf16x8 bi = *(const bf16x8*)&Wim[(lt * 16 + col) * KP + t * 32 + g4 * 8];
            accr[lt] = __builtin_amdgcn_mfma_f32_16x16x32_bf16(af, br, accr[lt], 0, 0, 0);
            acci[lt] = __builtin_amdgcn_mfma_f32_16x16x32_bf16(af, bi, acci[lt], 0, 0, 0);
        }
    }

    #pragma unroll
    for (int reg = 0; reg < 4; reg++) {
        int r = w * 16 + g4 * 4 + reg;   // C row = (lane>>4)*4+reg
        int m;
        if (wmode == 0) m = blockIdx.x * 64 + r;
        else {
            int k = blockIdx.x / 20; int pt = blockIdx.x - k * 20;
            m = (k * 8 + (r & 7)) * G + pt * 8 + (r >> 3);
        }
        #pragma unroll
        for (int lt = 0; lt < 10; lt++) {
            Bb[(size_t)m * G + lt * 16 + col] =
                packbf(alpha * accr[lt][reg], alpha * acci[lt][reg]);
        }
    }
}

// ---------------------------------------------------------------------------
// Stage 2 (MFMA): T[j][l][kd] = sum_p W[j][p]*B[kd][p][l], 8 kd per block.
// 2 waves (j-tile 32), W-frags hoisted to registers across kd loop,
// register accumulators, single LDS-transpose epilogue -> contiguous 32B
// stores of T (bf16-packed, kd-fast).
// ---------------------------------------------------------------------------
__global__ __launch_bounds__(128) void k_stage2(
    const unsigned int* __restrict__ Bb,
    const unsigned short* __restrict__ Wre,
    const unsigned short* __restrict__ Wim,
    unsigned int* __restrict__ T)
{
    __shared__ unsigned int sB[2560];   // B frag-stream for one kd (10 KB)
    __shared__ unsigned int sR[5120];   // result [ (j*16+l)*10 + kq ] (20 KB)

    int tid = threadIdx.x;
    int w = tid >> 6, lane = tid & 63;
    int col = lane & 15, g4 = lane >> 4;
    int kdg = blockIdx.x;
    int l0 = blockIdx.y * 16;
    int j0 = blockIdx.z * 32;

    int jrow = j0 + w * 16 + col;
    bf16x8 wrf[10], wif[10];
    #pragma unroll
    for (int t = 0; t < 10; t++) {
        wrf[t] = *(const bf16x8*)&Wre[jrow * KP + t * 32 + g4 * 8];
        wif[t] = *(const bf16x8*)&Wim[jrow * KP + t * 32 + g4 * 8];
    }

    f32x4 ar[8], ai[8];
    #pragma unroll
    for (int i = 0; i < 8; i++) { ar[i] = (f32x4)(0.f); ai[i] = (f32x4)(0.f); }

    #pragma unroll
    for (int kq = 0; kq < 8; kq++) {
        int kd = kdg * 8 + kq;
        __syncthreads();
        #pragma unroll 4
        for (int it = 0; it < 20; it++) {
            int idx = it * 128 + tid;
            int p = idx >> 4, l = idx & 15;
            int t_ = p >> 4, g = (p >> 2) & 3, j2 = p & 3;
            sB[(t_ * 64 + g * 16 + l) * 4 + j2] =
                Bb[((size_t)kd * G + p) * G + l0 + l];
        }
        __syncthreads();
        #pragma unroll
        for (int t = 0; t < 10; t++) {
            bf16x8 bf = *(const bf16x8*)&sB[(t * 64 + lane) * 4];
            ar[kq] = __builtin_amdgcn_mfma_f32_16x16x32_bf16(wrf[t], bf, ar[kq], 0, 0, 0);
            ai[kq] = __builtin_amdgcn_mfma_f32_16x16x32_bf16(wif[t], bf, ai[kq], 0, 0, 0);
        }
    }

    #pragma unroll
    for (int kq = 0; kq < 8; kq++)
        #pragma unroll
        for (int reg = 0; reg < 4; reg++) {
            int jj = w * 16 + g4 * 4 + reg;
            sR[(jj * 16 + col) * 10 + kq] = packbf(ar[kq][reg], ai[kq][reg]);
        }
    __syncthreads();
    #pragma unroll
    for (int it = 0; it < 4; it++) {
        int idx = it * 128 + tid;
        int jj = idx >> 4, l = idx & 15;
        const unsigned int* bp = &sR[(jj * 16 + l) * 10];
        uint2 q0 = *(const uint2*)(bp + 0);
        uint2 q1 = *(const uint2*)(bp + 2);
        uint2 q2 = *(const uint2*)(bp + 4);
        uint2 q3 = *(const uint2*)(bp + 6);
        size_t ta = ((size_t)((j0 + jj) * G + l0 + l)) * KD + kdg * 8;
        uint4 lo; lo.x = q0.x; lo.y = q0.y; lo.z = q1.x; lo.w = q1.y;
        uint4 hi; hi.x = q2.x; hi.y = q2.y; hi.z = q3.x; hi.w = q3.y;
        *(uint4*)&T[ta] = lo;
        *(uint4*)&T[ta + 4] = hi;
    }
}

// ---------------------------------------------------------------------------
// Sampler: 16 lanes/point, lane = k, handles all 8 d via 2x uint4 per corner.
// One __sincosf + 6 angle doublings give all octave frequencies.
// ---------------------------------------------------------------------------
__device__ __forceinline__ float plane_eval16(const unsigned int* __restrict__ T,
                                              float gy, float gx, float fc, int k)
{
    float iy = (gy + 1.0f) * 0.5f * (float)GM1;
    float ix = (gx + 1.0f) * 0.5f * (float)GM1;
    float iy0f = floorf(iy), ix0f = floorf(ix);
    float wy = iy - iy0f, wx = ix - ix0f;
    int iy0 = (int)iy0f, ix0 = (int)ix0f;
    int iy1 = min(iy0 + 1, GM1), ix1 = min(ix0 + 1, GM1);
    iy0 = max(min(iy0, GM1), 0); ix0 = max(min(ix0, GM1), 0);
    iy1 = max(iy1, 0); ix1 = max(ix1, 0);

    const unsigned int* c00 = &T[(size_t)(iy0 * G + ix0) * KD + k * 8];
    const unsigned int* c01 = &T[(size_t)(iy0 * G + ix1) * KD + k * 8];
    const unsigned int* c10 = &T[(size_t)(iy1 * G + ix0) * KD + k * 8];
    const unsigned int* c11 = &T[(size_t)(iy1 * G + ix1) * KD + k * 8];
    uint4 a00 = *(const uint4*)c00, b00 = *(const uint4*)(c00 + 4);
    uint4 a01 = *(const uint4*)c01, b01 = *(const uint4*)(c01 + 4);
    uint4 a10 = *(const uint4*)c10, b10 = *(const uint4*)(c10 + 4);
    uint4 a11 = *(const uint4*)c11, b11 = *(const uint4*)(c11 + 4);

    float w00 = (1.f - wx) * (1.f - wy), w01 = wx * (1.f - wy);
    float w10 = (1.f - wx) * wy,        w11 = wx * wy;

    float s1v, c1v;
    __sincosf(TWO_PI_F * fc, &s1v, &c1v);
    float cd[8], sd[8];
    cd[1] = c1v; sd[1] = s1v;
    #pragma unroll
    for (int d = 2; d < 8; d++) {
        float t2 = cd[d - 1] + cd[d - 1];
        cd[d] = __builtin_fmaf(t2, cd[d - 1], -1.0f);   // cos(2a)=2c^2-1
        sd[d] = t2 * sd[d - 1];                         // sin(2a)=2cs
    }

    float acc = 0.f;
#define TERM(u0, u1, u2, u3, C, S) { \
    float re = bfl(u0) * w00 + bfl(u1) * w01 + bfl(u2) * w10 + bfl(u3) * w11; \
    float im = bfh(u0) * w00 + bfh(u1) * w01 + bfh(u2) * w10 + bfh(u3) * w11; \
    acc += re * (C) - im * (S); }
    TERM(a00.x, a01.x, a10.x, a11.x, 1.0f, 0.0f)                       // d=0
    TERM(a00.y, a01.y, a10.y, a11.y, cd[1] + cd[1], sd[1] + sd[1])     // f=1
    TERM(a00.z, a01.z, a10.z, a11.z, cd[2] + cd[2], sd[2] + sd[2])     // f=2
    TERM(a00.w, a01.w, a10.w, a11.w, cd[3] + cd[3], sd[3] + sd[3])     // f=4
    TERM(b00.x, b01.x, b10.x, b11.x, cd[4] + cd[4], sd[4] + sd[4])     // f=8
    TERM(b00.y, b01.y, b10.y, b11.y, cd[5] + cd[5], sd[5] + sd[5])     // f=16
    TERM(b00.z, b01.z, b10.z, b11.z, cd[6] + cd[6], sd[6] + sd[6])     // f=32
    TERM(b00.w, b01.w, b10.w, b11.w, cd[7] + cd[7], sd[7] + sd[7])     // f=64
#undef TERM
    return acc;
}

__global__ __launch_bounds__(256) void k_sample(
    const float* __restrict__ xyz, const float* __restrict__ bound,
    const unsigned int* __restrict__ Tu, const unsigned int* __restrict__ Tv,
    const unsigned int* __restrict__ Tw,
    float* __restrict__ out, int N)
{
    int tid = threadIdx.x;
    int k = tid & 15;
    int n = blockIdx.x * 16 + (tid >> 4);
    if (n >= N) return;

    float invb = 1.0f / bound[0];
    float x = xyz[3 * n + 0] * invb;
    float y = xyz[3 * n + 1] * invb;
    float z = xyz[3 * n + 2] * invb;
    float xx = (x + 1.0f) * 0.5f;
    float yy = (y + 1.0f) * 0.5f;
    float zz = (z + 1.0f) * 0.5f;

    float acc = plane_eval16(Tu, y, z, xx, k)
              + plane_eval16(Tv, x, z, yy, k)
              + plane_eval16(Tw, y, x, zz, k);
    out[n * 16 + k] = acc;
}

// ---------------------------------------------------------------------------
extern "C" void kernel_launch(void* const* d_in, const int* in_sizes, int n_in,
                              void* d_out, int out_size, void* d_ws, size_t ws_size,
                              hipStream_t stream) {
    const float* xyz          = (const float*)d_in[0];
    const float* bound        = (const float*)d_in[1];
    const float* alpha_params = (const float*)d_in[2];
    const float* Pu_re = (const float*)d_in[3];
    const float* Pu_im = (const float*)d_in[4];
    const float* Pv_re = (const float*)d_in[5];
    const float* Pv_im = (const float*)d_in[6];
    const float* Pw_re = (const float*)d_in[7];
    const float* Pw_im = (const float*)d_in[8];
    float* out = (float*)d_out;
    int N = in_sizes[0] / 3;

    // ws: Wre 100KB | Wim 100KB | Bb 12.5MB | Tu|Tv|Tw 12.5MB each (bf16 packed)
    char* ws = (char*)d_ws;
    unsigned short* Wre = (unsigned short*)(ws);
    unsigned short* Wim = (unsigned short*)(ws + 102400);
    unsigned int*   Bb  = (unsigned int*)(ws + 204800);
    unsigned int*   Tu  = (unsigned int*)(ws + 204800 + 13107200);
    unsigned int*   Tv  = Tu + (size_t)G * G * KD;
    unsigned int*   Tw  = Tv + (size_t)G * G * KD;

    k_init_w<<<(G * KP + 255) / 256, 256, 0, stream>>>(Wre, Wim);

    dim3 g2(16, 10, 5);
    // Pu: (1,16,8,160,160): d=axis2(s=25600), p=y(s=160), q=z(s=1)
    k_stage1<<<320, 256, 0, stream>>>(Pu_re, Pu_im, alpha_params, Wre, Wim, Bb,
                                      204800, 25600, 160, 1, 0);
    k_stage2<<<g2, 128, 0, stream>>>(Bb, Wre, Wim, Tu);
    // Pv: (1,16,160,8,160): d=axis3(s=160), p=x(s=1280), q=z(s=1)
    k_stage1<<<320, 256, 0, stream>>>(Pv_re, Pv_im, alpha_params, Wre, Wim, Bb,
                                      204800, 160, 1280, 1, 0);
    k_stage2<<<g2, 128, 0, stream>>>(Bb, Wre, Wim, Tv);
    // Pw: (1,16,160,160,8): d=z(s=1), p=y(s=8), q=x(s=1280); custom (k,d,p) tiling
    k_stage1<<<320, 256, 0, stream>>>(Pw_re, Pw_im, alpha_params, Wre, Wim, Bb,
                                      204800, 1, 8, 1280, 1);
    k_stage2<<<g2, 128, 0, stream>>>(Bb, Wre, Wim, Tw);

    k_sample<<<N / 16, 256, 0, stream>>>(xyz, bound, Tu, Tv, Tw, out, N);
}

// Round 4
// 371.039 us; speedup vs baseline: 3.0590x; 1.2665x over previous
//
#include <hip/hip_runtime.h>
#include <hip/hip_bf16.h>

#define G 160
#define GM1 159
#define KD 128   // 16 k * 8 d complex channels
#define KP 320   // doubled K (re/im interleaved)
#define PLANE_U 3276800   // uints per plane of B/T (128*160*160)
#define TWO_PI_F 6.28318530717958647692f

typedef __attribute__((ext_vector_type(8))) short bf16x8;   // 4 VGPRs, 8 bf16
typedef __attribute__((ext_vector_type(4))) float f32x4;

__device__ __forceinline__ unsigned short f2bf(float x) {
    unsigned u = __float_as_uint(x);
    unsigned r = (u + 0x7FFFu + ((u >> 16) & 1u)) >> 16;   // RNE
    return (unsigned short)r;
}
__device__ __forceinline__ unsigned int packbf(float re, float im) {
    union { __hip_bfloat162 h; unsigned int u; } cv;
    cv.h = __float22bfloat162_rn(make_float2(re, im));      // v_cvt_pk_bf16_f32
    return cv.u;
}
__device__ __forceinline__ float bfl(unsigned u) { return __uint_as_float(u << 16); }
__device__ __forceinline__ float bfh(unsigned u) { return __uint_as_float(u & 0xffff0000u); }

// ---------------------------------------------------------------------------
// W tables, bf16, fragment-layout [row r][k'] (k'=2q interleaved):
//   k'=2q: (c, s)/160 ; k'=2q+1: (-s, c)/160  -> complex mult via doubled K.
// ---------------------------------------------------------------------------
__global__ void k_init_w(unsigned short* __restrict__ Wre,
                         unsigned short* __restrict__ Wim) {
    int idx = blockIdx.x * blockDim.x + threadIdx.x;
    if (idx >= G * KP) return;
    int r = idx / KP, kp = idx - r * KP;
    int q = kp >> 1;
    int m = (r * q) % G;
    float th = (float)m * (TWO_PI_F / (float)G);
    float s, c;
    __sincosf(th, &s, &c);
    c *= (1.0f / (float)G);
    s *= (1.0f / (float)G);
    float vr, vi;
    if ((kp & 1) == 0) { vr = c;  vi = s; }
    else               { vr = -s; vi = c; }
    Wre[idx] = f2bf(vr);
    Wim[idx] = f2bf(vi);
}

// ---------------------------------------------------------------------------
// Pack Pw (k, y, x, d) [strides 204800, 8, 1280, 1] into packed-bf16 rows
// Apw[m = (k*8+d)*160 + y][q = x], contiguous in q. LDS 64x33 transpose tile.
// ---------------------------------------------------------------------------
__global__ __launch_bounds__(256) void k_packw(
    const float* __restrict__ Are, const float* __restrict__ Aim,
    unsigned int* __restrict__ Apw)
{
    __shared__ unsigned int sT[64 * 33];
    int k  = blockIdx.x;        // 0..15
    int pc = blockIdx.y;        // 0..19   (y-chunk of 8)
    int q0 = blockIdx.z * 32;   // 0..4 *32 (x)
    int tid = threadIdx.x;

    int i = tid & 63, qo = tid >> 6;           // i = pr*8 + d (input-contiguous)
    size_t base = (size_t)k * 204800 + (size_t)pc * 64 + i;
    #pragma unroll
    for (int qc = 0; qc < 8; qc++) {
        int q = q0 + qo * 8 + qc;
        float r  = Are[base + (size_t)q * 1280];
        float im = Aim[base + (size_t)q * 1280];
        sT[i * 33 + qo * 8 + qc] = packbf(r, im);
    }
    __syncthreads();
    int qp = tid & 31, mo = tid >> 5;          // output: 32 q x 8 m-groups
    #pragma unroll
    for (int mc = 0; mc < 8; mc++) {
        int d = mo, pr = mc;
        int m = (k * 8 + d) * G + pc * 8 + pr;
        Apw[(size_t)m * G + q0 + qp] = sT[(mc * 8 + mo) * 33 + qp];
    }
}

// ---------------------------------------------------------------------------
// Stage 1 (all 3 planes): B[m=(kd,p)][l] = alpha * sum_q A*W[l][q]
// 4 waves/block, wave = one 16-row m-tile; A-frags preloaded to registers,
// W streamed from L2. Epilogue writes B in MFMA B-frag order: one coalesced
// uint4 per lane per l-tile:
//   Bfrag[plane][ (kd*10+lt)*2560 + (ptile*64 + lane)*4 + (p&3) ]
// ---------------------------------------------------------------------------
__global__ __launch_bounds__(256) void k_stage1(
    const float* __restrict__ Pu_re, const float* __restrict__ Pu_im,
    const float* __restrict__ Pv_re, const float* __restrict__ Pv_im,
    const unsigned int* __restrict__ Apw,
    const float* __restrict__ alpha_params,
    const unsigned short* __restrict__ Wre,
    const unsigned short* __restrict__ Wim,
    unsigned int* __restrict__ Bfrag)
{
    int tid = threadIdx.x;
    int w = tid >> 6, lane = tid & 63;
    int col = lane & 15, g4 = lane >> 4;
    int bx = blockIdx.x;
    int plane = bx / 320;
    int mtl = (bx - plane * 320) * 4 + w;      // m-tile 0..1279
    int kd = mtl / 10, ptile = mtl - kd * 10;

    float ap = alpha_params[0];
    float bxv = 10.0f * ap;
    float alpha = (bxv > 1.0f) ? ap : log1pf(expf(fminf(bxv, 1.0f))) * 0.1f;

    bf16x8 afr[10];
    if (plane == 2) {
        const unsigned int* a2 = Apw + (size_t)(mtl * 16 + col) * G + g4 * 4;
        #pragma unroll
        for (int t = 0; t < 10; t++) {
            union { uint4 u; bf16x8 b; } cv;
            cv.u = *(const uint4*)(a2 + t * 16);
            afr[t] = cv.b;
        }
    } else {
        const float *Ar, *Ai; int sd_, sp_;
        if (plane == 0) { Ar = Pu_re; Ai = Pu_im; sd_ = 25600; sp_ = 160; }
        else            { Ar = Pv_re; Ai = Pv_im; sd_ = 160;   sp_ = 1280; }
        int m = mtl * 16 + col;
        int k = m / 1280; int rm = m - k * 1280;
        int d = rm / 160; int p = rm - d * 160;
        size_t abase = (size_t)k * 204800 + (size_t)d * sd_ + (size_t)p * sp_ + g4 * 4;
        #pragma unroll
        for (int t = 0; t < 10; t++) {
            float4 vr = *(const float4*)(Ar + abase + t * 16);
            float4 vi = *(const float4*)(Ai + abase + t * 16);
            union { unsigned int u[4]; bf16x8 b; } cv;
            cv.u[0] = packbf(vr.x, vi.x); cv.u[1] = packbf(vr.y, vi.y);
            cv.u[2] = packbf(vr.z, vi.z); cv.u[3] = packbf(vr.w, vi.w);
            afr[t] = cv.b;
        }
    }

    unsigned int* Bout = Bfrag + (size_t)plane * PLANE_U + (size_t)kd * 10 * 2560;

    for (int lt = 0; lt < 10; lt++) {
        f32x4 ar = (f32x4)(0.f), ai = (f32x4)(0.f);
        #pragma unroll
        for (int t = 0; t < 10; t++) {
            bf16x8 br = *(const bf16x8*)&Wre[(lt * 16 + col) * KP + t * 32 + g4 * 8];
            bf16x8 bi = *(const bf16x8*)&Wim[(lt * 16 + col) * KP + t * 32 + g4 * 8];
            ar = __builtin_amdgcn_mfma_f32_16x16x32_bf16(afr[t], br, ar, 0, 0, 0);
            ai = __builtin_amdgcn_mfma_f32_16x16x32_bf16(afr[t], bi, ai, 0, 0, 0);
        }
        uint4 o;
        o.x = packbf(alpha * ar[0], alpha * ai[0]);
        o.y = packbf(alpha * ar[1], alpha * ai[1]);
        o.z = packbf(alpha * ar[2], alpha * ai[2]);
        o.w = packbf(alpha * ar[3], alpha * ai[3]);
        *(uint4*)(Bout + (size_t)lt * 2560 + (ptile * 64 + lane) * 4) = o;
    }
}

// ---------------------------------------------------------------------------
// Stage 2 (all 3 planes): T[j][l][kd] = sum_p W[j][p]*B[kd][p][l]
// Block = 640 thr (10 waves, wave = one 16-row j-tile), 4 kd, one 16-l tile.
// Staging: coalesced uint4 -> LDS frag stream, ONE barrier. T stores 16 B.
// ---------------------------------------------------------------------------
__global__ __launch_bounds__(640) void k_stage2(
    const unsigned int* __restrict__ Bfrag,
    const unsigned short* __restrict__ Wre,
    const unsigned short* __restrict__ Wim,
    unsigned int* __restrict__ Tall)
{
    __shared__ __align__(16) unsigned int sB[10240];   // 40 KB: 4 kd x 2560
    int tid = threadIdx.x;
    int w = tid >> 6, lane = tid & 63;
    int col = lane & 15, g4 = lane >> 4;
    int kdg = blockIdx.x;        // 0..31
    int lt  = blockIdx.y;        // 0..9
    int plane = blockIdx.z;      // 0..2

    const unsigned int* Bp = Bfrag + (size_t)plane * PLANE_U;
    #pragma unroll
    for (int kq = 0; kq < 4; kq++) {
        uint4 v = *(const uint4*)(Bp + ((size_t)(kdg * 4 + kq) * 10 + lt) * 2560 + tid * 4);
        *(uint4*)(sB + kq * 2560 + tid * 4) = v;
    }
    __syncthreads();

    int jrow = w * 16 + col;
    f32x4 ar[4], ai[4];
    #pragma unroll
    for (int i = 0; i < 4; i++) { ar[i] = (f32x4)(0.f); ai[i] = (f32x4)(0.f); }

    #pragma unroll
    for (int t = 0; t < 10; t++) {
        bf16x8 wr = *(const bf16x8*)&Wre[jrow * KP + t * 32 + g4 * 8];
        bf16x8 wi = *(const bf16x8*)&Wim[jrow * KP + t * 32 + g4 * 8];
        #pragma unroll
        for (int kq = 0; kq < 4; kq++) {
            bf16x8 bf = *(const bf16x8*)&sB[kq * 2560 + (t * 64 + lane) * 4];
            ar[kq] = __builtin_amdgcn_mfma_f32_16x16x32_bf16(wr, bf, ar[kq], 0, 0, 0);
            ai[kq] = __builtin_amdgcn_mfma_f32_16x16x32_bf16(wi, bf, ai[kq], 0, 0, 0);
        }
    }

    unsigned int* Tp = Tall + (size_t)plane * PLANE_U;
    #pragma unroll
    for (int reg = 0; reg < 4; reg++) {
        int j = w * 16 + g4 * 4 + reg;
        int l = lt * 16 + col;
        uint4 o;
        o.x = packbf(ar[0][reg], ai[0][reg]);
        o.y = packbf(ar[1][reg], ai[1][reg]);
        o.z = packbf(ar[2][reg], ai[2][reg]);
        o.w = packbf(ar[3][reg], ai[3][reg]);
        *(uint4*)(Tp + ((size_t)(j * G + l)) * KD + kdg * 4) = o;
    }
}

// ---------------------------------------------------------------------------
// Sampler: 16 lanes/point, lane = k, all 8 d via 2x uint4 per corner.
// ---------------------------------------------------------------------------
__device__ __forceinline__ float plane_eval16(const unsigned int* __restrict__ T,
                                              float gy, float gx, float fc, int k)
{
    float iy = (gy + 1.0f) * 0.5f * (float)GM1;
    float ix = (gx + 1.0f) * 0.5f * (float)GM1;
    float iy0f = floorf(iy), ix0f = floorf(ix);
    float wy = iy - iy0f, wx = ix - ix0f;
    int iy0 = (int)iy0f, ix0 = (int)ix0f;
    int iy1 = min(iy0 + 1, GM1), ix1 = min(ix0 + 1, GM1);
    iy0 = max(min(iy0, GM1), 0); ix0 = max(min(ix0, GM1), 0);
    iy1 = max(iy1, 0); ix1 = max(ix1, 0);

    const unsigned int* c00 = &T[(size_t)(iy0 * G + ix0) * KD + k * 8];
    const unsigned int* c01 = &T[(size_t)(iy0 * G + ix1) * KD + k * 8];
    const unsigned int* c10 = &T[(size_t)(iy1 * G + ix0) * KD + k * 8];
    const unsigned int* c11 = &T[(size_t)(iy1 * G + ix1) * KD + k * 8];
    uint4 a00 = *(const uint4*)c00, b00 = *(const uint4*)(c00 + 4);
    uint4 a01 = *(const uint4*)c01, b01 = *(const uint4*)(c01 + 4);
    uint4 a10 = *(const uint4*)c10, b10 = *(const uint4*)(c10 + 4);
    uint4 a11 = *(const uint4*)c11, b11 = *(const uint4*)(c11 + 4);

    float w00 = (1.f - wx) * (1.f - wy), w01 = wx * (1.f - wy);
    float w10 = (1.f - wx) * wy,        w11 = wx * wy;

    float s1v, c1v;
    __sincosf(TWO_PI_F * fc, &s1v, &c1v);
    float cd[8], sd[8];
    cd[1] = c1v; sd[1] = s1v;
    #pragma unroll
    for (int d = 2; d < 8; d++) {
        float t2 = cd[d - 1] + cd[d - 1];
        cd[d] = __builtin_fmaf(t2, cd[d - 1], -1.0f);
        sd[d] = t2 * sd[d - 1];
    }

    float acc = 0.f;
#define TERM(u0, u1, u2, u3, C, S) { \
    float re = bfl(u0) * w00 + bfl(u1) * w01 + bfl(u2) * w10 + bfl(u3) * w11; \
    float im = bfh(u0) * w00 + bfh(u1) * w01 + bfh(u2) * w10 + bfh(u3) * w11; \
    acc += re * (C) - im * (S); }
    TERM(a00.x, a01.x, a10.x, a11.x, 1.0f, 0.0f)
    TERM(a00.y, a01.y, a10.y, a11.y, cd[1] + cd[1], sd[1] + sd[1])
    TERM(a00.z, a01.z, a10.z, a11.z, cd[2] + cd[2], sd[2] + sd[2])
    TERM(a00.w, a01.w, a10.w, a11.w, cd[3] + cd[3], sd[3] + sd[3])
    TERM(b00.x, b01.x, b10.x, b11.x, cd[4] + cd[4], sd[4] + sd[4])
    TERM(b00.y, b01.y, b10.y, b11.y, cd[5] + cd[5], sd[5] + sd[5])
    TERM(b00.z, b01.z, b10.z, b11.z, cd[6] + cd[6], sd[6] + sd[6])
    TERM(b00.w, b01.w, b10.w, b11.w, cd[7] + cd[7], sd[7] + sd[7])
#undef TERM
    return acc;
}

__global__ __launch_bounds__(256) void k_sample(
    const float* __restrict__ xyz, const float* __restrict__ bound,
    const unsigned int* __restrict__ Tu, const unsigned int* __restrict__ Tv,
    const unsigned int* __restrict__ Tw,
    float* __restrict__ out, int N)
{
    int tid = threadIdx.x;
    int k = tid & 15;
    int n = blockIdx.x * 16 + (tid >> 4);
    if (n >= N) return;

    float invb = 1.0f / bound[0];
    float x = xyz[3 * n + 0] * invb;
    float y = xyz[3 * n + 1] * invb;
    float z = xyz[3 * n + 2] * invb;
    float xx = (x + 1.0f) * 0.5f;
    float yy = (y + 1.0f) * 0.5f;
    float zz = (z + 1.0f) * 0.5f;

    float acc = plane_eval16(Tu, y, z, xx, k)
              + plane_eval16(Tv, x, z, yy, k)
              + plane_eval16(Tw, y, x, zz, k);
    out[n * 16 + k] = acc;
}

// ---------------------------------------------------------------------------
extern "C" void kernel_launch(void* const* d_in, const int* in_sizes, int n_in,
                              void* d_out, int out_size, void* d_ws, size_t ws_size,
                              hipStream_t stream) {
    const float* xyz          = (const float*)d_in[0];
    const float* bound        = (const float*)d_in[1];
    const float* alpha_params = (const float*)d_in[2];
    const float* Pu_re = (const float*)d_in[3];
    const float* Pu_im = (const float*)d_in[4];
    const float* Pv_re = (const float*)d_in[5];
    const float* Pv_im = (const float*)d_in[6];
    const float* Pw_re = (const float*)d_in[7];
    const float* Pw_im = (const float*)d_in[8];
    float* out = (float*)d_out;
    int N = in_sizes[0] / 3;

    // ws: Wre 100K | Wim 100K | Apw 12.5M | Bfrag 37.5M | T 37.5M  (~92 MB)
    char* ws = (char*)d_ws;
    unsigned short* Wre  = (unsigned short*)(ws);
    unsigned short* Wim  = (unsigned short*)(ws + 102400);
    unsigned int*   Apw  = (unsigned int*)(ws + 204800);
    unsigned int*   Bfr  = (unsigned int*)(ws + 204800 + 13107200);
    unsigned int*   Tall = (unsigned int*)(ws + 204800 + 13107200 + 39321600);
    unsigned int*   Tu   = Tall;
    unsigned int*   Tv   = Tall + (size_t)PLANE_U;
    unsigned int*   Tw   = Tall + (size_t)2 * PLANE_U;

    k_init_w<<<(G * KP + 255) / 256, 256, 0, stream>>>(Wre, Wim);
    k_packw<<<dim3(16, 20, 5), 256, 0, stream>>>(Pw_re, Pw_im, Apw);
    k_stage1<<<960, 256, 0, stream>>>(Pu_re, Pu_im, Pv_re, Pv_im, Apw,
                                      alpha_params, Wre, Wim, Bfr);
    k_stage2<<<dim3(32, 10, 3), 640, 0, stream>>>(Bfr, Wre, Wim, Tall);
    k_sample<<<N / 16, 256, 0, stream>>>(xyz, bound, Tu, Tv, Tw, out, N);
}

// Round 5
// 290.208 us; speedup vs baseline: 3.9111x; 1.2785x over previous
//
#include <hip/hip_runtime.h>
#include <hip/hip_bf16.h>

#define G 160
#define GM1 159
#define KD 128    // 16 k * 8 d complex channels
#define KP 320    // doubled K (re/im interleaved)
#define PLANE_U 3276800   // uints per plane of B/T (128*160*160)
#define TWO_PI_F 6.28318530717958647692f

typedef __attribute__((ext_vector_type(8))) short bf16x8;   // 4 VGPRs, 8 bf16
typedef __attribute__((ext_vector_type(4))) float f32x4;

__device__ __forceinline__ unsigned short f2bf(float x) {
    unsigned u = __float_as_uint(x);
    unsigned r = (u + 0x7FFFu + ((u >> 16) & 1u)) >> 16;   // RNE
    return (unsigned short)r;
}
__device__ __forceinline__ unsigned int packbf(float re, float im) {
    union { __hip_bfloat162 h; unsigned int u; } cv;
    cv.h = __float22bfloat162_rn(make_float2(re, im));      // v_cvt_pk_bf16_f32
    return cv.u;
}
__device__ __forceinline__ float bfl(unsigned u) { return __uint_as_float(u << 16); }
__device__ __forceinline__ float bfh(unsigned u) { return __uint_as_float(u & 0xffff0000u); }
// Wim fragment uint from Wre fragment uint: (c,-s) -> (s,c)
__device__ __forceinline__ unsigned int wim_of(unsigned int u) {
    return ((u << 16) | (u >> 16)) ^ 0x00008000u;
}

// ---------------------------------------------------------------------------
// Wre table only, bf16, fragment layout [row r][k'] (k'=2q interleaved):
//   k'=2q: c/160 ; k'=2q+1: -s/160.  Wim derived in-register via wim_of().
// ---------------------------------------------------------------------------
__global__ void k_init_w(unsigned short* __restrict__ Wre) {
    int idx = blockIdx.x * blockDim.x + threadIdx.x;
    if (idx >= G * KP) return;
    int r = idx / KP, kp = idx - r * KP;
    int q = kp >> 1;
    int m = (r * q) % G;
    float th = (float)m * (TWO_PI_F / (float)G);
    float s, c;
    __sincosf(th, &s, &c);
    Wre[idx] = f2bf(((kp & 1) == 0 ? c : -s) * (1.0f / (float)G));
}

// ---------------------------------------------------------------------------
// Pack Pw (k, y, x, d) [strides 204800, 8, 1280, 1] into packed-bf16 rows
// Apw[m = (k*8+d)*160 + y][q = x], contiguous in q. LDS 64x33 transpose tile.
// ---------------------------------------------------------------------------
__global__ __launch_bounds__(256) void k_packw(
    const float* __restrict__ Are, const float* __restrict__ Aim,
    unsigned int* __restrict__ Apw)
{
    __shared__ unsigned int sT[64 * 33];
    int k  = blockIdx.x;        // 0..15
    int pc = blockIdx.y;        // 0..19   (y-chunk of 8)
    int q0 = blockIdx.z * 32;   // 0..4 *32 (x)
    int tid = threadIdx.x;

    int i = tid & 63, qo = tid >> 6;
    size_t base = (size_t)k * 204800 + (size_t)pc * 64 + i;
    #pragma unroll
    for (int qc = 0; qc < 8; qc++) {
        int q = q0 + qo * 8 + qc;
        float r  = Are[base + (size_t)q * 1280];
        float im = Aim[base + (size_t)q * 1280];
        sT[i * 33 + qo * 8 + qc] = packbf(r, im);
    }
    __syncthreads();
    int qp = tid & 31, mo = tid >> 5;
    #pragma unroll
    for (int mc = 0; mc < 8; mc++) {
        int m = (k * 8 + mo) * G + pc * 8 + mc;
        Apw[(size_t)m * G + q0 + qp] = sT[(mc * 8 + mo) * 33 + qp];
    }
}

// ---------------------------------------------------------------------------
// Stage 1: B[m=(kd,p)][l] = alpha * sum_q A*W[l][q].  Wave = 2 m-tiles
// (A-frags in registers), W streamed from L2 (br only, bi derived) so each
// 16B W load feeds 4 MFMAs. No LDS. Output in MFMA B-frag order:
//   Bfrag[plane][(kd*10+lt)*2560 + ptile*256 + lane*4 + j2]
// ---------------------------------------------------------------------------
__global__ __launch_bounds__(512) void k_stage1(
    const float* __restrict__ Pu_re, const float* __restrict__ Pu_im,
    const float* __restrict__ Pv_re, const float* __restrict__ Pv_im,
    const unsigned int* __restrict__ Apw,
    const float* __restrict__ alpha_params,
    const unsigned short* __restrict__ Wre,
    unsigned int* __restrict__ Bfrag)
{
    int tid = threadIdx.x;
    int w = tid >> 6, lane = tid & 63;
    int col = lane & 15, g4 = lane >> 4;
    int gw = blockIdx.x * 8 + w;          // 0..1919 wave-tasks
    int mt0 = gw * 2;                     // global m-tile pair
    int plane = mt0 / 1280;
    int mtl0 = mt0 - plane * 1280;        // plane-local tile idx (even)

    float ap = alpha_params[0];
    float bxv = 10.0f * ap;
    float alpha = (bxv > 1.0f) ? ap : log1pf(expf(fminf(bxv, 1.0f))) * 0.1f;

    bf16x8 afr[2][10];
    #pragma unroll
    for (int ti = 0; ti < 2; ti++) {
        int mtl = mtl0 + ti;
        if (plane == 2) {
            const unsigned int* a2 = Apw + (size_t)(mtl * 16 + col) * G + g4 * 4;
            #pragma unroll
            for (int t = 0; t < 10; t++) {
                union { uint4 u; bf16x8 b; } cv;
                cv.u = *(const uint4*)(a2 + t * 16);
                afr[ti][t] = cv.b;
            }
        } else {
            const float *Ar, *Ai; int sd_, sp_;
            if (plane == 0) { Ar = Pu_re; Ai = Pu_im; sd_ = 25600; sp_ = 160; }
            else            { Ar = Pv_re; Ai = Pv_im; sd_ = 160;   sp_ = 1280; }
            int m = mtl * 16 + col;
            int k = m / 1280; int rm = m - k * 1280;
            int d = rm / 160; int p = rm - d * 160;
            size_t abase = (size_t)k * 204800 + (size_t)d * sd_ + (size_t)p * sp_ + g4 * 4;
            #pragma unroll
            for (int t = 0; t < 10; t++) {
                float4 vr = *(const float4*)(Ar + abase + t * 16);
                float4 vi = *(const float4*)(Ai + abase + t * 16);
                union { unsigned int u[4]; bf16x8 b; } cv;
                cv.u[0] = packbf(vr.x, vi.x); cv.u[1] = packbf(vr.y, vi.y);
                cv.u[2] = packbf(vr.z, vi.z); cv.u[3] = packbf(vr.w, vi.w);
                afr[ti][t] = cv.b;
            }
        }
    }

    unsigned int* Bpl = Bfrag + (size_t)plane * PLANE_U;
    int kd0 = mtl0 / 10, pt0 = mtl0 - kd0 * 10;
    int mtl1 = mtl0 + 1;
    int kd1 = mtl1 / 10, pt1 = mtl1 - kd1 * 10;

    for (int lt = 0; lt < 10; lt++) {
        f32x4 ar0 = (f32x4)(0.f), ai0 = (f32x4)(0.f);
        f32x4 ar1 = (f32x4)(0.f), ai1 = (f32x4)(0.f);
        const unsigned short* wp = &Wre[(lt * 16 + col) * KP + g4 * 8];
        #pragma unroll
        for (int t = 0; t < 10; t++) {
            union { uint4 u; bf16x8 b; } cr, ci;
            cr.u = *(const uint4*)(wp + t * 32);
            ci.u.x = wim_of(cr.u.x); ci.u.y = wim_of(cr.u.y);
            ci.u.z = wim_of(cr.u.z); ci.u.w = wim_of(cr.u.w);
            ar0 = __builtin_amdgcn_mfma_f32_16x16x32_bf16(afr[0][t], cr.b, ar0, 0, 0, 0);
            ai0 = __builtin_amdgcn_mfma_f32_16x16x32_bf16(afr[0][t], ci.b, ai0, 0, 0, 0);
            ar1 = __builtin_amdgcn_mfma_f32_16x16x32_bf16(afr[1][t], cr.b, ar1, 0, 0, 0);
            ai1 = __builtin_amdgcn_mfma_f32_16x16x32_bf16(afr[1][t], ci.b, ai1, 0, 0, 0);
        }
        uint4 o0, o1;
        o0.x = packbf(alpha * ar0[0], alpha * ai0[0]);
        o0.y = packbf(alpha * ar0[1], alpha * ai0[1]);
        o0.z = packbf(alpha * ar0[2], alpha * ai0[2]);
        o0.w = packbf(alpha * ar0[3], alpha * ai0[3]);
        o1.x = packbf(alpha * ar1[0], alpha * ai1[0]);
        o1.y = packbf(alpha * ar1[1], alpha * ai1[1]);
        o1.z = packbf(alpha * ar1[2], alpha * ai1[2]);
        o1.w = packbf(alpha * ar1[3], alpha * ai1[3]);
        *(uint4*)(Bpl + (size_t)(kd0 * 10 + lt) * 2560 + pt0 * 256 + lane * 4) = o0;
        *(uint4*)(Bpl + (size_t)(kd1 * 10 + lt) * 2560 + pt1 * 256 + lane * 4) = o1;
    }
}

// ---------------------------------------------------------------------------
// Stage 2: T[j][l][kd] = sum_p W[j][p]*B[kd][p][l].
// Block = (kd-octet, l-tile, plane), 640 thr = 10 waves = 10 j-tiles on ONE
// CU. B octet staged once into 80KB LDS (coalesced, one barrier); W A-frags
// register-hoisted (br only, bi derived). T stores 32B-contiguous.
// ---------------------------------------------------------------------------
__global__ __launch_bounds__(640) void k_stage2(
    const unsigned int* __restrict__ Bfrag,
    const unsigned short* __restrict__ Wre,
    unsigned int* __restrict__ Tall)
{
    __shared__ __align__(16) unsigned int sB[20480];   // 80 KB: 8 kd x 2560
    int tid = threadIdx.x;
    int w = tid >> 6, lane = tid & 63;     // w = jt
    int col = lane & 15, g4 = lane >> 4;
    int kdo = blockIdx.x;        // 0..15
    int lt  = blockIdx.y;        // 0..9
    int plane = blockIdx.z;      // 0..2

    const unsigned int* Bp = Bfrag + (size_t)plane * PLANE_U;
    #pragma unroll
    for (int i = 0; i < 8; i++) {
        uint4 v = *(const uint4*)(Bp + ((size_t)(kdo * 8 + i) * 10 + lt) * 2560 + tid * 4);
        *(uint4*)(sB + i * 2560 + tid * 4) = v;
    }

    // hoist W A-frags (jt fixed per wave)
    bf16x8 wfr[10];
    const unsigned short* wp = &Wre[(w * 16 + col) * KP + g4 * 8];
    #pragma unroll
    for (int t = 0; t < 10; t++)
        wfr[t] = *(const bf16x8*)(wp + t * 32);

    __syncthreads();

    f32x4 ar[8], ai[8];
    #pragma unroll
    for (int i = 0; i < 8; i++) { ar[i] = (f32x4)(0.f); ai[i] = (f32x4)(0.f); }

    #pragma unroll
    for (int t = 0; t < 10; t++) {
        union { bf16x8 b; uint4 u; } cr, ci;
        cr.b = wfr[t];
        ci.u.x = wim_of(cr.u.x); ci.u.y = wim_of(cr.u.y);
        ci.u.z = wim_of(cr.u.z); ci.u.w = wim_of(cr.u.w);
        #pragma unroll
        for (int kq = 0; kq < 8; kq++) {
            bf16x8 bf = *(const bf16x8*)&sB[kq * 2560 + (t * 64 + lane) * 4];
            ar[kq] = __builtin_amdgcn_mfma_f32_16x16x32_bf16(cr.b, bf, ar[kq], 0, 0, 0);
            ai[kq] = __builtin_amdgcn_mfma_f32_16x16x32_bf16(ci.b, bf, ai[kq], 0, 0, 0);
        }
    }

    unsigned int* Tp = Tall + (size_t)plane * PLANE_U;
    #pragma unroll
    for (int reg = 0; reg < 4; reg++) {
        int j = w * 16 + g4 * 4 + reg;
        int l = lt * 16 + col;
        uint4 o0, o1;
        o0.x = packbf(ar[0][reg], ai[0][reg]);
        o0.y = packbf(ar[1][reg], ai[1][reg]);
        o0.z = packbf(ar[2][reg], ai[2][reg]);
        o0.w = packbf(ar[3][reg], ai[3][reg]);
        o1.x = packbf(ar[4][reg], ai[4][reg]);
        o1.y = packbf(ar[5][reg], ai[5][reg]);
        o1.z = packbf(ar[6][reg], ai[6][reg]);
        o1.w = packbf(ar[7][reg], ai[7][reg]);
        size_t ta = ((size_t)(j * G + l)) * KD + kdo * 8;
        *(uint4*)(Tp + ta)     = o0;
        *(uint4*)(Tp + ta + 4) = o1;
    }
}

// ---------------------------------------------------------------------------
// Sampler: 16 lanes/point, lane = k, all 8 d via 2x uint4 per corner.
// ---------------------------------------------------------------------------
__device__ __forceinline__ float plane_eval16(const unsigned int* __restrict__ T,
                                              float gy, float gx, float fc, int k)
{
    float iy = (gy + 1.0f) * 0.5f * (float)GM1;
    float ix = (gx + 1.0f) * 0.5f * (float)GM1;
    float iy0f = floorf(iy), ix0f = floorf(ix);
    float wy = iy - iy0f, wx = ix - ix0f;
    int iy0 = (int)iy0f, ix0 = (int)ix0f;
    int iy1 = min(iy0 + 1, GM1), ix1 = min(ix0 + 1, GM1);
    iy0 = max(min(iy0, GM1), 0); ix0 = max(min(ix0, GM1), 0);
    iy1 = max(iy1, 0); ix1 = max(ix1, 0);

    const unsigned int* c00 = &T[(size_t)(iy0 * G + ix0) * KD + k * 8];
    const unsigned int* c01 = &T[(size_t)(iy0 * G + ix1) * KD + k * 8];
    const unsigned int* c10 = &T[(size_t)(iy1 * G + ix0) * KD + k * 8];
    const unsigned int* c11 = &T[(size_t)(iy1 * G + ix1) * KD + k * 8];
    uint4 a00 = *(const uint4*)c00, b00 = *(const uint4*)(c00 + 4);
    uint4 a01 = *(const uint4*)c01, b01 = *(const uint4*)(c01 + 4);
    uint4 a10 = *(const uint4*)c10, b10 = *(const uint4*)(c10 + 4);
    uint4 a11 = *(const uint4*)c11, b11 = *(const uint4*)(c11 + 4);

    float w00 = (1.f - wx) * (1.f - wy), w01 = wx * (1.f - wy);
    float w10 = (1.f - wx) * wy,        w11 = wx * wy;

    float s1v, c1v;
    __sincosf(TWO_PI_F * fc, &s1v, &c1v);
    float cd[8], sd[8];
    cd[1] = c1v; sd[1] = s1v;
    #pragma unroll
    for (int d = 2; d < 8; d++) {
        float t2 = cd[d - 1] + cd[d - 1];
        cd[d] = __builtin_fmaf(t2, cd[d - 1], -1.0f);
        sd[d] = t2 * sd[d - 1];
    }

    float acc = 0.f;
#define TERM(u0, u1, u2, u3, C, S) { \
    float re = bfl(u0) * w00 + bfl(u1) * w01 + bfl(u2) * w10 + bfl(u3) * w11; \
    float im = bfh(u0) * w00 + bfh(u1) * w01 + bfh(u2) * w10 + bfh(u3) * w11; \
    acc += re * (C) - im * (S); }
    TERM(a00.x, a01.x, a10.x, a11.x, 1.0f, 0.0f)
    TERM(a00.y, a01.y, a10.y, a11.y, cd[1] + cd[1], sd[1] + sd[1])
    TERM(a00.z, a01.z, a10.z, a11.z, cd[2] + cd[2], sd[2] + sd[2])
    TERM(a00.w, a01.w, a10.w, a11.w, cd[3] + cd[3], sd[3] + sd[3])
    TERM(b00.x, b01.x, b10.x, b11.x, cd[4] + cd[4], sd[4] + sd[4])
    TERM(b00.y, b01.y, b10.y, b11.y, cd[5] + cd[5], sd[5] + sd[5])
    TERM(b00.z, b01.z, b10.z, b11.z, cd[6] + cd[6], sd[6] + sd[6])
    TERM(b00.w, b01.w, b10.w, b11.w, cd[7] + cd[7], sd[7] + sd[7])
#undef TERM
    return acc;
}

__global__ __launch_bounds__(256) void k_sample(
    const float* __restrict__ xyz, const float* __restrict__ bound,
    const unsigned int* __restrict__ Tu, const unsigned int* __restrict__ Tv,
    const unsigned int* __restrict__ Tw,
    float* __restrict__ out, int N)
{
    int tid = threadIdx.x;
    int k = tid & 15;
    int n = blockIdx.x * 16 + (tid >> 4);
    if (n >= N) return;

    float invb = 1.0f / bound[0];
    float x = xyz[3 * n + 0] * invb;
    float y = xyz[3 * n + 1] * invb;
    float z = xyz[3 * n + 2] * invb;
    float xx = (x + 1.0f) * 0.5f;
    float yy = (y + 1.0f) * 0.5f;
    float zz = (z + 1.0f) * 0.5f;

    float acc = plane_eval16(Tu, y, z, xx, k)
              + plane_eval16(Tv, x, z, yy, k)
              + plane_eval16(Tw, y, x, zz, k);
    out[n * 16 + k] = acc;
}

// ---------------------------------------------------------------------------
extern "C" void kernel_launch(void* const* d_in, const int* in_sizes, int n_in,
                              void* d_out, int out_size, void* d_ws, size_t ws_size,
                              hipStream_t stream) {
    const float* xyz          = (const float*)d_in[0];
    const float* bound        = (const float*)d_in[1];
    const float* alpha_params = (const float*)d_in[2];
    const float* Pu_re = (const float*)d_in[3];
    const float* Pu_im = (const float*)d_in[4];
    const float* Pv_re = (const float*)d_in[5];
    const float* Pv_im = (const float*)d_in[6];
    const float* Pw_re = (const float*)d_in[7];
    const float* Pw_im = (const float*)d_in[8];
    float* out = (float*)d_out;
    int N = in_sizes[0] / 3;

    // ws: Wre 100K | Apw 12.5M | Bfrag 37.5M | T 37.5M  (~92 MB)
    char* ws = (char*)d_ws;
    unsigned short* Wre  = (unsigned short*)(ws);
    unsigned int*   Apw  = (unsigned int*)(ws + 102400);
    unsigned int*   Bfr  = (unsigned int*)(ws + 102400 + 13107200);
    unsigned int*   Tall = (unsigned int*)(ws + 102400 + 13107200 + 39321600);
    unsigned int*   Tu   = Tall;
    unsigned int*   Tv   = Tall + (size_t)PLANE_U;
    unsigned int*   Tw   = Tall + (size_t)2 * PLANE_U;

    k_init_w<<<(G * KP + 255) / 256, 256, 0, stream>>>(Wre);
    k_packw<<<dim3(16, 20, 5), 256, 0, stream>>>(Pw_re, Pw_im, Apw);
    k_stage1<<<240, 512, 0, stream>>>(Pu_re, Pu_im, Pv_re, Pv_im, Apw,
                                      alpha_params, Wre, Bfr);
    k_stage2<<<dim3(16, 10, 3), 640, 0, stream>>>(Bfr, Wre, Tall);
    k_sample<<<N / 16, 256, 0, stream>>>(xyz, bound, Tu, Tv, Tw, out, N);
}

// Round 6
// 263.217 us; speedup vs baseline: 4.3121x; 1.1025x over previous
//
#include <hip/hip_runtime.h>
#include <hip/hip_bf16.h>

#define G 160
#define GM1 159
#define KD 128    // 16 k * 8 d complex channels
#define KP 320    // doubled K (re/im interleaved)
#define PLANE_U 3276800   // uints per plane of B/T (128*160*160)
#define NBUCK 32768       // 2^15 morton buckets (5 bits/axis)
#define TWO_PI_F 6.28318530717958647692f

typedef __attribute__((ext_vector_type(8))) short bf16x8;   // 4 VGPRs, 8 bf16
typedef __attribute__((ext_vector_type(4))) float f32x4;

__device__ __forceinline__ unsigned short f2bf(float x) {
    unsigned u = __float_as_uint(x);
    unsigned r = (u + 0x7FFFu + ((u >> 16) & 1u)) >> 16;   // RNE
    return (unsigned short)r;
}
__device__ __forceinline__ unsigned int packbf(float re, float im) {
    union { __hip_bfloat162 h; unsigned int u; } cv;
    cv.h = __float22bfloat162_rn(make_float2(re, im));      // v_cvt_pk_bf16_f32
    return cv.u;
}
__device__ __forceinline__ float bfl(unsigned u) { return __uint_as_float(u << 16); }
__device__ __forceinline__ float bfh(unsigned u) { return __uint_as_float(u & 0xffff0000u); }
// Wim fragment uint from Wre fragment uint: (c,-s) -> (s,c)
__device__ __forceinline__ unsigned int wim_of(unsigned int u) {
    return ((u << 16) | (u >> 16)) ^ 0x00008000u;
}
__device__ __forceinline__ unsigned part1by2(unsigned x) {   // 5-bit spread
    x &= 0x3FF;
    x = (x | (x << 16)) & 0xFF0000FFu;
    x = (x | (x << 8))  & 0x0300F00Fu;
    x = (x | (x << 4))  & 0x030C30C3u;
    x = (x | (x << 2))  & 0x09249249u;
    return x;
}
__device__ __forceinline__ unsigned morton_key(float x, float y, float z) {
    // coords in [-1,1] -> 5-bit cells
    int cx = min(max((int)((x + 1.0f) * 16.0f), 0), 31);
    int cy = min(max((int)((y + 1.0f) * 16.0f), 0), 31);
    int cz = min(max((int)((z + 1.0f) * 16.0f), 0), 31);
    return part1by2(cx) | (part1by2(cy) << 1) | (part1by2(cz) << 2);
}

// ---------------------------------------------------------------------------
// Wre table only, bf16, fragment layout [row r][k'] (k'=2q interleaved):
//   k'=2q: c/160 ; k'=2q+1: -s/160.  Wim derived in-register via wim_of().
// ---------------------------------------------------------------------------
__global__ void k_init_w(unsigned short* __restrict__ Wre) {
    int idx = blockIdx.x * blockDim.x + threadIdx.x;
    if (idx >= G * KP) return;
    int r = idx / KP, kp = idx - r * KP;
    int q = kp >> 1;
    int m = (r * q) % G;
    float th = (float)m * (TWO_PI_F / (float)G);
    float s, c;
    __sincosf(th, &s, &c);
    Wre[idx] = f2bf(((kp & 1) == 0 ? c : -s) * (1.0f / (float)G));
}

// ---------------------------------------------------------------------------
// Morton counting sort: zero -> hist -> scan -> scatter(sorted float4)
// ---------------------------------------------------------------------------
__global__ void k_zero(unsigned int* __restrict__ counts) {
    int i = blockIdx.x * blockDim.x + threadIdx.x;
    if (i < NBUCK) counts[i] = 0;
}

__global__ __launch_bounds__(256) void k_hist(
    const float* __restrict__ xyz, const float* __restrict__ bound,
    unsigned int* __restrict__ counts, int N)
{
    int i = blockIdx.x * blockDim.x + threadIdx.x;
    if (i >= N) return;
    float invb = 1.0f / bound[0];
    float x = xyz[3 * i + 0] * invb;
    float y = xyz[3 * i + 1] * invb;
    float z = xyz[3 * i + 2] * invb;
    atomicAdd(&counts[morton_key(x, y, z)], 1u);
}

__global__ __launch_bounds__(1024) void k_scan(
    const unsigned int* __restrict__ counts,
    unsigned int* __restrict__ cursors)
{
    __shared__ unsigned int sT[1024];
    int t = threadIdx.x;
    unsigned int local[32];
    unsigned int s = 0;
    #pragma unroll
    for (int i = 0; i < 32; i++) { local[i] = counts[t * 32 + i]; s += local[i]; }
    sT[t] = s;
    __syncthreads();
    // Hillis-Steele inclusive scan
    for (int off = 1; off < 1024; off <<= 1) {
        unsigned int v = (t >= off) ? sT[t - off] : 0u;
        __syncthreads();
        sT[t] += v;
        __syncthreads();
    }
    unsigned int run = (t > 0) ? sT[t - 1] : 0u;
    #pragma unroll
    for (int i = 0; i < 32; i++) { cursors[t * 32 + i] = run; run += local[i]; }
}

__global__ __launch_bounds__(256) void k_scatter(
    const float* __restrict__ xyz, const float* __restrict__ bound,
    unsigned int* __restrict__ cursors, float4* __restrict__ sxyz, int N)
{
    int i = blockIdx.x * blockDim.x + threadIdx.x;
    if (i >= N) return;
    float invb = 1.0f / bound[0];
    float x = xyz[3 * i + 0] * invb;
    float y = xyz[3 * i + 1] * invb;
    float z = xyz[3 * i + 2] * invb;
    unsigned int pos = atomicAdd(&cursors[morton_key(x, y, z)], 1u);
    sxyz[pos] = make_float4(x, y, z, __int_as_float(i));
}

// ---------------------------------------------------------------------------
// Pack Pw (k, y, x, d) [strides 204800, 8, 1280, 1] into packed-bf16 rows
// Apw[m = (k*8+d)*160 + y][q = x], contiguous in q. LDS 64x33 transpose tile.
// ---------------------------------------------------------------------------
__global__ __launch_bounds__(256) void k_packw(
    const float* __restrict__ Are, const float* __restrict__ Aim,
    unsigned int* __restrict__ Apw)
{
    __shared__ unsigned int sT[64 * 33];
    int k  = blockIdx.x;        // 0..15
    int pc = blockIdx.y;        // 0..19   (y-chunk of 8)
    int q0 = blockIdx.z * 32;   // 0..4 *32 (x)
    int tid = threadIdx.x;

    int i = tid & 63, qo = tid >> 6;
    size_t base = (size_t)k * 204800 + (size_t)pc * 64 + i;
    #pragma unroll
    for (int qc = 0; qc < 8; qc++) {
        int q = q0 + qo * 8 + qc;
        float r  = Are[base + (size_t)q * 1280];
        float im = Aim[base + (size_t)q * 1280];
        sT[i * 33 + qo * 8 + qc] = packbf(r, im);
    }
    __syncthreads();
    int qp = tid & 31, mo = tid >> 5;
    #pragma unroll
    for (int mc = 0; mc < 8; mc++) {
        int m = (k * 8 + mo) * G + pc * 8 + mc;
        Apw[(size_t)m * G + q0 + qp] = sT[(mc * 8 + mo) * 33 + qp];
    }
}

// ---------------------------------------------------------------------------
// Stage 1: B[m=(kd,p)][l] = alpha * sum_q A*W[l][q].  Wave = 2 m-tiles
// (A-frags in registers), W streamed from L2 (br only, bi derived) so each
// 16B W load feeds 4 MFMAs. No LDS. Output in MFMA B-frag order.
// ---------------------------------------------------------------------------
__global__ __launch_bounds__(512) void k_stage1(
    const float* __restrict__ Pu_re, const float* __restrict__ Pu_im,
    const float* __restrict__ Pv_re, const float* __restrict__ Pv_im,
    const unsigned int* __restrict__ Apw,
    const float* __restrict__ alpha_params,
    const unsigned short* __restrict__ Wre,
    unsigned int* __restrict__ Bfrag)
{
    int tid = threadIdx.x;
    int w = tid >> 6, lane = tid & 63;
    int col = lane & 15, g4 = lane >> 4;
    int gw = blockIdx.x * 8 + w;
    int mt0 = gw * 2;
    int plane = mt0 / 1280;
    int mtl0 = mt0 - plane * 1280;

    float ap = alpha_params[0];
    float bxv = 10.0f * ap;
    float alpha = (bxv > 1.0f) ? ap : log1pf(expf(fminf(bxv, 1.0f))) * 0.1f;

    bf16x8 afr[2][10];
    #pragma unroll
    for (int ti = 0; ti < 2; ti++) {
        int mtl = mtl0 + ti;
        if (plane == 2) {
            const unsigned int* a2 = Apw + (size_t)(mtl * 16 + col) * G + g4 * 4;
            #pragma unroll
            for (int t = 0; t < 10; t++) {
                union { uint4 u; bf16x8 b; } cv;
                cv.u = *(const uint4*)(a2 + t * 16);
                afr[ti][t] = cv.b;
            }
        } else {
            const float *Ar, *Ai; int sd_, sp_;
            if (plane == 0) { Ar = Pu_re; Ai = Pu_im; sd_ = 25600; sp_ = 160; }
            else            { Ar = Pv_re; Ai = Pv_im; sd_ = 160;   sp_ = 1280; }
            int m = mtl * 16 + col;
            int k = m / 1280; int rm = m - k * 1280;
            int d = rm / 160; int p = rm - d * 160;
            size_t abase = (size_t)k * 204800 + (size_t)d * sd_ + (size_t)p * sp_ + g4 * 4;
            #pragma unroll
            for (int t = 0; t < 10; t++) {
                float4 vr = *(const float4*)(Ar + abase + t * 16);
                float4 vi = *(const float4*)(Ai + abase + t * 16);
                union { unsigned int u[4]; bf16x8 b; } cv;
                cv.u[0] = packbf(vr.x, vi.x); cv.u[1] = packbf(vr.y, vi.y);
                cv.u[2] = packbf(vr.z, vi.z); cv.u[3] = packbf(vr.w, vi.w);
                afr[ti][t] = cv.b;
            }
        }
    }

    unsigned int* Bpl = Bfrag + (size_t)plane * PLANE_U;
    int kd0 = mtl0 / 10, pt0 = mtl0 - kd0 * 10;
    int mtl1 = mtl0 + 1;
    int kd1 = mtl1 / 10, pt1 = mtl1 - kd1 * 10;

    for (int lt = 0; lt < 10; lt++) {
        f32x4 ar0 = (f32x4)(0.f), ai0 = (f32x4)(0.f);
        f32x4 ar1 = (f32x4)(0.f), ai1 = (f32x4)(0.f);
        const unsigned short* wp = &Wre[(lt * 16 + col) * KP + g4 * 8];
        #pragma unroll
        for (int t = 0; t < 10; t++) {
            union { uint4 u; bf16x8 b; } cr, ci;
            cr.u = *(const uint4*)(wp + t * 32);
            ci.u.x = wim_of(cr.u.x); ci.u.y = wim_of(cr.u.y);
            ci.u.z = wim_of(cr.u.z); ci.u.w = wim_of(cr.u.w);
            ar0 = __builtin_amdgcn_mfma_f32_16x16x32_bf16(afr[0][t], cr.b, ar0, 0, 0, 0);
            ai0 = __builtin_amdgcn_mfma_f32_16x16x32_bf16(afr[0][t], ci.b, ai0, 0, 0, 0);
            ar1 = __builtin_amdgcn_mfma_f32_16x16x32_bf16(afr[1][t], cr.b, ar1, 0, 0, 0);
            ai1 = __builtin_amdgcn_mfma_f32_16x16x32_bf16(afr[1][t], ci.b, ai1, 0, 0, 0);
        }
        uint4 o0, o1;
        o0.x = packbf(alpha * ar0[0], alpha * ai0[0]);
        o0.y = packbf(alpha * ar0[1], alpha * ai0[1]);
        o0.z = packbf(alpha * ar0[2], alpha * ai0[2]);
        o0.w = packbf(alpha * ar0[3], alpha * ai0[3]);
        o1.x = packbf(alpha * ar1[0], alpha * ai1[0]);
        o1.y = packbf(alpha * ar1[1], alpha * ai1[1]);
        o1.z = packbf(alpha * ar1[2], alpha * ai1[2]);
        o1.w = packbf(alpha * ar1[3], alpha * ai1[3]);
        *(uint4*)(Bpl + (size_t)(kd0 * 10 + lt) * 2560 + pt0 * 256 + lane * 4) = o0;
        *(uint4*)(Bpl + (size_t)(kd1 * 10 + lt) * 2560 + pt1 * 256 + lane * 4) = o1;
    }
}

// ---------------------------------------------------------------------------
// Stage 2: T[j][l][kd] = sum_p W[j][p]*B[kd][p][l].
// Block = (kd-octet, l-tile, plane), 640 thr = 10 waves = 10 j-tiles.
// B octet staged once into 80KB LDS; W A-frags register-hoisted.
// ---------------------------------------------------------------------------
__global__ __launch_bounds__(640) void k_stage2(
    const unsigned int* __restrict__ Bfrag,
    const unsigned short* __restrict__ Wre,
    unsigned int* __restrict__ Tall)
{
    __shared__ __align__(16) unsigned int sB[20480];   // 80 KB: 8 kd x 2560
    int tid = threadIdx.x;
    int w = tid >> 6, lane = tid & 63;
    int col = lane & 15, g4 = lane >> 4;
    int kdo = blockIdx.x;
    int lt  = blockIdx.y;
    int plane = blockIdx.z;

    const unsigned int* Bp = Bfrag + (size_t)plane * PLANE_U;
    #pragma unroll
    for (int i = 0; i < 8; i++) {
        uint4 v = *(const uint4*)(Bp + ((size_t)(kdo * 8 + i) * 10 + lt) * 2560 + tid * 4);
        *(uint4*)(sB + i * 2560 + tid * 4) = v;
    }

    bf16x8 wfr[10];
    const unsigned short* wp = &Wre[(w * 16 + col) * KP + g4 * 8];
    #pragma unroll
    for (int t = 0; t < 10; t++)
        wfr[t] = *(const bf16x8*)(wp + t * 32);

    __syncthreads();

    f32x4 ar[8], ai[8];
    #pragma unroll
    for (int i = 0; i < 8; i++) { ar[i] = (f32x4)(0.f); ai[i] = (f32x4)(0.f); }

    #pragma unroll
    for (int t = 0; t < 10; t++) {
        union { bf16x8 b; uint4 u; } cr, ci;
        cr.b = wfr[t];
        ci.u.x = wim_of(cr.u.x); ci.u.y = wim_of(cr.u.y);
        ci.u.z = wim_of(cr.u.z); ci.u.w = wim_of(cr.u.w);
        #pragma unroll
        for (int kq = 0; kq < 8; kq++) {
            bf16x8 bf = *(const bf16x8*)&sB[kq * 2560 + (t * 64 + lane) * 4];
            ar[kq] = __builtin_amdgcn_mfma_f32_16x16x32_bf16(cr.b, bf, ar[kq], 0, 0, 0);
            ai[kq] = __builtin_amdgcn_mfma_f32_16x16x32_bf16(ci.b, bf, ai[kq], 0, 0, 0);
        }
    }

    unsigned int* Tp = Tall + (size_t)plane * PLANE_U;
    #pragma unroll
    for (int reg = 0; reg < 4; reg++) {
        int j = w * 16 + g4 * 4 + reg;
        int l = lt * 16 + col;
        uint4 o0, o1;
        o0.x = packbf(ar[0][reg], ai[0][reg]);
        o0.y = packbf(ar[1][reg], ai[1][reg]);
        o0.z = packbf(ar[2][reg], ai[2][reg]);
        o0.w = packbf(ar[3][reg], ai[3][reg]);
        o1.x = packbf(ar[4][reg], ai[4][reg]);
        o1.y = packbf(ar[5][reg], ai[5][reg]);
        o1.z = packbf(ar[6][reg], ai[6][reg]);
        o1.w = packbf(ar[7][reg], ai[7][reg]);
        size_t ta = ((size_t)(j * G + l)) * KD + kdo * 8;
        *(uint4*)(Tp + ta)     = o0;
        *(uint4*)(Tp + ta + 4) = o1;
    }
}

// ---------------------------------------------------------------------------
// Sampler: 16 lanes/point, lane = k; points in Morton-sorted order with
// XCD-aware segment swizzle (blockIdx%8 -> contiguous eighth of sorted list).
// ---------------------------------------------------------------------------
__device__ __forceinline__ float plane_eval16(const unsigned int* __restrict__ T,
                                              float gy, float gx, float fc, int k)
{
    float iy = (gy + 1.0f) * 0.5f * (float)GM1;
    float ix = (gx + 1.0f) * 0.5f * (float)GM1;
    float iy0f = floorf(iy), ix0f = floorf(ix);
    float wy = iy - iy0f, wx = ix - ix0f;
    int iy0 = (int)iy0f, ix0 = (int)ix0f;
    int iy1 = min(iy0 + 1, GM1), ix1 = min(ix0 + 1, GM1);
    iy0 = max(min(iy0, GM1), 0); ix0 = max(min(ix0, GM1), 0);
    iy1 = max(iy1, 0); ix1 = max(ix1, 0);

    const unsigned int* c00 = &T[(size_t)(iy0 * G + ix0) * KD + k * 8];
    const unsigned int* c01 = &T[(size_t)(iy0 * G + ix1) * KD + k * 8];
    const unsigned int* c10 = &T[(size_t)(iy1 * G + ix0) * KD + k * 8];
    const unsigned int* c11 = &T[(size_t)(iy1 * G + ix1) * KD + k * 8];
    uint4 a00 = *(const uint4*)c00, b00 = *(const uint4*)(c00 + 4);
    uint4 a01 = *(const uint4*)c01, b01 = *(const uint4*)(c01 + 4);
    uint4 a10 = *(const uint4*)c10, b10 = *(const uint4*)(c10 + 4);
    uint4 a11 = *(const uint4*)c11, b11 = *(const uint4*)(c11 + 4);

    float w00 = (1.f - wx) * (1.f - wy), w01 = wx * (1.f - wy);
    float w10 = (1.f - wx) * wy,        w11 = wx * wy;

    float s1v, c1v;
    __sincosf(TWO_PI_F * fc, &s1v, &c1v);
    float cd[8], sd[8];
    cd[1] = c1v; sd[1] = s1v;
    #pragma unroll
    for (int d = 2; d < 8; d++) {
        float t2 = cd[d - 1] + cd[d - 1];
        cd[d] = __builtin_fmaf(t2, cd[d - 1], -1.0f);
        sd[d] = t2 * sd[d - 1];
    }

    float acc = 0.f;
#define TERM(u0, u1, u2, u3, C, S) { \
    float re = bfl(u0) * w00 + bfl(u1) * w01 + bfl(u2) * w10 + bfl(u3) * w11; \
    float im = bfh(u0) * w00 + bfh(u1) * w01 + bfh(u2) * w10 + bfh(u3) * w11; \
    acc += re * (C) - im * (S); }
    TERM(a00.x, a01.x, a10.x, a11.x, 1.0f, 0.0f)
    TERM(a00.y, a01.y, a10.y, a11.y, cd[1] + cd[1], sd[1] + sd[1])
    TERM(a00.z, a01.z, a10.z, a11.z, cd[2] + cd[2], sd[2] + sd[2])
    TERM(a00.w, a01.w, a10.w, a11.w, cd[3] + cd[3], sd[3] + sd[3])
    TERM(b00.x, b01.x, b10.x, b11.x, cd[4] + cd[4], sd[4] + sd[4])
    TERM(b00.y, b01.y, b10.y, b11.y, cd[5] + cd[5], sd[5] + sd[5])
    TERM(b00.z, b01.z, b10.z, b11.z, cd[6] + cd[6], sd[6] + sd[6])
    TERM(b00.w, b01.w, b10.w, b11.w, cd[7] + cd[7], sd[7] + sd[7])
#undef TERM
    return acc;
}

__global__ __launch_bounds__(256) void k_sample(
    const float4* __restrict__ sxyz,
    const unsigned int* __restrict__ Tu, const unsigned int* __restrict__ Tv,
    const unsigned int* __restrict__ Tw,
    float* __restrict__ out, int N)
{
    int tid = threadIdx.x;
    int k = tid & 15;
    int nblocks = (N + 15) / 16;
    int seg = blockIdx.x & 7;
    int segblocks = nblocks >> 3;                 // N multiple of 128
    int pid = (seg * segblocks + (blockIdx.x >> 3)) * 16 + (tid >> 4);
    if (pid >= N) return;

    float4 pw = sxyz[pid];
    int n = __float_as_int(pw.w);
    float x = pw.x, y = pw.y, z = pw.z;
    float xx = (x + 1.0f) * 0.5f;
    float yy = (y + 1.0f) * 0.5f;
    float zz = (z + 1.0f) * 0.5f;

    float acc = plane_eval16(Tu, y, z, xx, k)
              + plane_eval16(Tv, x, z, yy, k)
              + plane_eval16(Tw, y, x, zz, k);
    out[n * 16 + k] = acc;
}

// ---------------------------------------------------------------------------
extern "C" void kernel_launch(void* const* d_in, const int* in_sizes, int n_in,
                              void* d_out, int out_size, void* d_ws, size_t ws_size,
                              hipStream_t stream) {
    const float* xyz          = (const float*)d_in[0];
    const float* bound        = (const float*)d_in[1];
    const float* alpha_params = (const float*)d_in[2];
    const float* Pu_re = (const float*)d_in[3];
    const float* Pu_im = (const float*)d_in[4];
    const float* Pv_re = (const float*)d_in[5];
    const float* Pv_im = (const float*)d_in[6];
    const float* Pw_re = (const float*)d_in[7];
    const float* Pw_im = (const float*)d_in[8];
    float* out = (float*)d_out;
    int N = in_sizes[0] / 3;

    // ws: Wre 100K | Apw 12.5M | Bfrag 37.5M | T 37.5M | counts 128K |
    //     cursors 128K | sxyz 2M   (~90.5 MB)
    char* ws = (char*)d_ws;
    unsigned short* Wre  = (unsigned short*)(ws);
    unsigned int*   Apw  = (unsigned int*)(ws + 102400);
    unsigned int*   Bfr  = (unsigned int*)(ws + 102400 + 13107200);
    unsigned int*   Tall = (unsigned int*)(ws + 102400 + 13107200 + 39321600);
    char*           ws2  = ws + 102400 + 13107200 + 39321600 + 39321600;
    unsigned int*   counts  = (unsigned int*)(ws2);
    unsigned int*   cursors = (unsigned int*)(ws2 + 131072);
    float4*         sxyz    = (float4*)(ws2 + 262144);
    unsigned int*   Tu   = Tall;
    unsigned int*   Tv   = Tall + (size_t)PLANE_U;
    unsigned int*   Tw   = Tall + (size_t)2 * PLANE_U;

    // point sort chain
    k_zero<<<NBUCK / 256, 256, 0, stream>>>(counts);
    k_hist<<<(N + 255) / 256, 256, 0, stream>>>(xyz, bound, counts, N);
    k_scan<<<1, 1024, 0, stream>>>(counts, cursors);
    k_scatter<<<(N + 255) / 256, 256, 0, stream>>>(xyz, bound, cursors, sxyz, N);

    // DFT pipeline
    k_init_w<<<(G * KP + 255) / 256, 256, 0, stream>>>(Wre);
    k_packw<<<dim3(16, 20, 5), 256, 0, stream>>>(Pw_re, Pw_im, Apw);
    k_stage1<<<240, 512, 0, stream>>>(Pu_re, Pu_im, Pv_re, Pv_im, Apw,
                                      alpha_params, Wre, Bfr);
    k_stage2<<<dim3(16, 10, 3), 640, 0, stream>>>(Bfr, Wre, Tall);

    k_sample<<<(N + 15) / 16, 256, 0, stream>>>(sxyz, Tu, Tv, Tw, out, N);
}

// Round 7
// 262.042 us; speedup vs baseline: 4.3314x; 1.0045x over previous
//
#include <hip/hip_runtime.h>
#include <hip/hip_bf16.h>

#define G 160
#define GM1 159
#define KD 128    // 16 k * 8 d complex channels
#define KP 320    // doubled K (re/im interleaved)
#define PLANE_U 3276800   // uints per plane of B/T (128*160*160)
#define NBUCK 4096        // 2^12 morton buckets (4 bits/axis)
#define TWO_PI_F 6.28318530717958647692f

typedef __attribute__((ext_vector_type(8))) short bf16x8;   // 4 VGPRs, 8 bf16
typedef __attribute__((ext_vector_type(4))) float f32x4;

__device__ __forceinline__ unsigned short f2bf(float x) {
    unsigned u = __float_as_uint(x);
    unsigned r = (u + 0x7FFFu + ((u >> 16) & 1u)) >> 16;   // RNE
    return (unsigned short)r;
}
__device__ __forceinline__ unsigned int packbf(float re, float im) {
    union { __hip_bfloat162 h; unsigned int u; } cv;
    cv.h = __float22bfloat162_rn(make_float2(re, im));      // v_cvt_pk_bf16_f32
    return cv.u;
}
__device__ __forceinline__ float bfl(unsigned u) { return __uint_as_float(u << 16); }
__device__ __forceinline__ float bfh(unsigned u) { return __uint_as_float(u & 0xffff0000u); }
// Wim fragment uint from Wre fragment uint: (c,-s) -> (s,c)
__device__ __forceinline__ unsigned int wim_of(unsigned int u) {
    return ((u << 16) | (u >> 16)) ^ 0x00008000u;
}
__device__ __forceinline__ unsigned part1by2(unsigned x) {
    x &= 0x3FF;
    x = (x | (x << 16)) & 0xFF0000FFu;
    x = (x | (x << 8))  & 0x0300F00Fu;
    x = (x | (x << 4))  & 0x030C30C3u;
    x = (x | (x << 2))  & 0x09249249u;
    return x;
}
__device__ __forceinline__ unsigned morton_key(float x, float y, float z) {
    int cx = min(max((int)((x + 1.0f) * 8.0f), 0), 15);
    int cy = min(max((int)((y + 1.0f) * 8.0f), 0), 15);
    int cz = min(max((int)((z + 1.0f) * 8.0f), 0), 15);
    return part1by2(cx) | (part1by2(cy) << 1) | (part1by2(cz) << 2);   // 12 bits
}

// ---------------------------------------------------------------------------
// Fused preprocessing: [0,16) zero counts | [16,216) W init | [216,1816) packw
// ---------------------------------------------------------------------------
__global__ __launch_bounds__(256) void k_prep(
    const float* __restrict__ Pw_re, const float* __restrict__ Pw_im,
    unsigned int* __restrict__ Apw, unsigned short* __restrict__ Wre,
    unsigned int* __restrict__ counts)
{
    __shared__ unsigned int sT[64 * 33];
    int b = blockIdx.x;
    int tid = threadIdx.x;
    if (b < 16) {                         // zero morton counters
        counts[b * 256 + tid] = 0;
        return;
    }
    if (b < 216) {                        // Wre table: [row r][k'] bf16
        int idx = (b - 16) * 256 + tid;   // < 51200
        int r = idx / KP, kp = idx - r * KP;
        int q = kp >> 1;
        int m = (r * q) % G;
        float th = (float)m * (TWO_PI_F / (float)G);
        float s, c;
        __sincosf(th, &s, &c);
        Wre[idx] = f2bf(((kp & 1) == 0 ? c : -s) * (1.0f / (float)G));
        return;
    }
    // packw: Pw (k,y,x,d) [204800, 8, 1280, 1] -> Apw[m=(k*8+d)*160+y][q=x]
    int b2 = b - 216;                     // 0..1599
    int k  = b2 / 100;
    int rem = b2 - k * 100;
    int pc = rem / 5;
    int q0 = (rem - pc * 5) * 32;

    int i = tid & 63, qo = tid >> 6;
    size_t base = (size_t)k * 204800 + (size_t)pc * 64 + i;
    #pragma unroll
    for (int qc = 0; qc < 8; qc++) {
        int q = q0 + qo * 8 + qc;
        float r  = Pw_re[base + (size_t)q * 1280];
        float im = Pw_im[base + (size_t)q * 1280];
        sT[i * 33 + qo * 8 + qc] = packbf(r, im);
    }
    __syncthreads();
    int qp = tid & 31, mo = tid >> 5;
    #pragma unroll
    for (int mc = 0; mc < 8; mc++) {
        int m = (k * 8 + mo) * G + pc * 8 + mc;
        Apw[(size_t)m * G + q0 + qp] = sT[(mc * 8 + mo) * 33 + qp];
    }
}

// ---------------------------------------------------------------------------
// Morton counting sort: hist -> scan -> scatter(sorted float4)
// ---------------------------------------------------------------------------
__global__ __launch_bounds__(256) void k_hist(
    const float* __restrict__ xyz, const float* __restrict__ bound,
    unsigned int* __restrict__ counts, int N)
{
    int i = blockIdx.x * blockDim.x + threadIdx.x;
    if (i >= N) return;
    float invb = 1.0f / bound[0];
    float x = xyz[3 * i + 0] * invb;
    float y = xyz[3 * i + 1] * invb;
    float z = xyz[3 * i + 2] * invb;
    atomicAdd(&counts[morton_key(x, y, z)], 1u);
}

__global__ __launch_bounds__(1024) void k_scan(
    const unsigned int* __restrict__ counts,
    unsigned int* __restrict__ cursors)
{
    __shared__ unsigned int sT[1024];
    int t = threadIdx.x;
    unsigned int local[4];
    unsigned int s = 0;
    #pragma unroll
    for (int i = 0; i < 4; i++) { local[i] = counts[t * 4 + i]; s += local[i]; }
    sT[t] = s;
    __syncthreads();
    for (int off = 1; off < 1024; off <<= 1) {
        unsigned int v = (t >= off) ? sT[t - off] : 0u;
        __syncthreads();
        sT[t] += v;
        __syncthreads();
    }
    unsigned int run = (t > 0) ? sT[t - 1] : 0u;
    #pragma unroll
    for (int i = 0; i < 4; i++) { cursors[t * 4 + i] = run; run += local[i]; }
}

__global__ __launch_bounds__(256) void k_scatter(
    const float* __restrict__ xyz, const float* __restrict__ bound,
    unsigned int* __restrict__ cursors, float4* __restrict__ sxyz, int N)
{
    int i = blockIdx.x * blockDim.x + threadIdx.x;
    if (i >= N) return;
    float invb = 1.0f / bound[0];
    float x = xyz[3 * i + 0] * invb;
    float y = xyz[3 * i + 1] * invb;
    float z = xyz[3 * i + 2] * invb;
    unsigned int pos = atomicAdd(&cursors[morton_key(x, y, z)], 1u);
    sxyz[pos] = make_float4(x, y, z, __int_as_float(i));
}

// ---------------------------------------------------------------------------
// Stage 1: B[m=(kd,p)][l] = alpha * sum_q A*W[l][q].  Wave = 2 m-tiles
// (A-frags in registers), W streamed from L2 (br only, bi derived) so each
// 16B W load feeds 4 MFMAs. No LDS. Output in MFMA B-frag order.
// ---------------------------------------------------------------------------
__global__ __launch_bounds__(512) void k_stage1(
    const float* __restrict__ Pu_re, const float* __restrict__ Pu_im,
    const float* __restrict__ Pv_re, const float* __restrict__ Pv_im,
    const unsigned int* __restrict__ Apw,
    const float* __restrict__ alpha_params,
    const unsigned short* __restrict__ Wre,
    unsigned int* __restrict__ Bfrag)
{
    int tid = threadIdx.x;
    int w = tid >> 6, lane = tid & 63;
    int col = lane & 15, g4 = lane >> 4;
    int gw = blockIdx.x * 8 + w;
    int mt0 = gw * 2;
    int plane = mt0 / 1280;
    int mtl0 = mt0 - plane * 1280;

    float ap = alpha_params[0];
    float bxv = 10.0f * ap;
    float alpha = (bxv > 1.0f) ? ap : log1pf(expf(fminf(bxv, 1.0f))) * 0.1f;

    bf16x8 afr[2][10];
    #pragma unroll
    for (int ti = 0; ti < 2; ti++) {
        int mtl = mtl0 + ti;
        if (plane == 2) {
            const unsigned int* a2 = Apw + (size_t)(mtl * 16 + col) * G + g4 * 4;
            #pragma unroll
            for (int t = 0; t < 10; t++) {
                union { uint4 u; bf16x8 b; } cv;
                cv.u = *(const uint4*)(a2 + t * 16);
                afr[ti][t] = cv.b;
            }
        } else {
            const float *Ar, *Ai; int sd_, sp_;
            if (plane == 0) { Ar = Pu_re; Ai = Pu_im; sd_ = 25600; sp_ = 160; }
            else            { Ar = Pv_re; Ai = Pv_im; sd_ = 160;   sp_ = 1280; }
            int m = mtl * 16 + col;
            int k = m / 1280; int rm = m - k * 1280;
            int d = rm / 160; int p = rm - d * 160;
            size_t abase = (size_t)k * 204800 + (size_t)d * sd_ + (size_t)p * sp_ + g4 * 4;
            #pragma unroll
            for (int t = 0; t < 10; t++) {
                float4 vr = *(const float4*)(Ar + abase + t * 16);
                float4 vi = *(const float4*)(Ai + abase + t * 16);
                union { unsigned int u[4]; bf16x8 b; } cv;
                cv.u[0] = packbf(vr.x, vi.x); cv.u[1] = packbf(vr.y, vi.y);
                cv.u[2] = packbf(vr.z, vi.z); cv.u[3] = packbf(vr.w, vi.w);
                afr[ti][t] = cv.b;
            }
        }
    }

    unsigned int* Bpl = Bfrag + (size_t)plane * PLANE_U;
    int kd0 = mtl0 / 10, pt0 = mtl0 - kd0 * 10;
    int mtl1 = mtl0 + 1;
    int kd1 = mtl1 / 10, pt1 = mtl1 - kd1 * 10;

    for (int lt = 0; lt < 10; lt++) {
        f32x4 ar0 = (f32x4)(0.f), ai0 = (f32x4)(0.f);
        f32x4 ar1 = (f32x4)(0.f), ai1 = (f32x4)(0.f);
        const unsigned short* wp = &Wre[(lt * 16 + col) * KP + g4 * 8];
        #pragma unroll
        for (int t = 0; t < 10; t++) {
            union { uint4 u; bf16x8 b; } cr, ci;
            cr.u = *(const uint4*)(wp + t * 32);
            ci.u.x = wim_of(cr.u.x); ci.u.y = wim_of(cr.u.y);
            ci.u.z = wim_of(cr.u.z); ci.u.w = wim_of(cr.u.w);
            ar0 = __builtin_amdgcn_mfma_f32_16x16x32_bf16(afr[0][t], cr.b, ar0, 0, 0, 0);
            ai0 = __builtin_amdgcn_mfma_f32_16x16x32_bf16(afr[0][t], ci.b, ai0, 0, 0, 0);
            ar1 = __builtin_amdgcn_mfma_f32_16x16x32_bf16(afr[1][t], cr.b, ar1, 0, 0, 0);
            ai1 = __builtin_amdgcn_mfma_f32_16x16x32_bf16(afr[1][t], ci.b, ai1, 0, 0, 0);
        }
        uint4 o0, o1;
        o0.x = packbf(alpha * ar0[0], alpha * ai0[0]);
        o0.y = packbf(alpha * ar0[1], alpha * ai0[1]);
        o0.z = packbf(alpha * ar0[2], alpha * ai0[2]);
        o0.w = packbf(alpha * ar0[3], alpha * ai0[3]);
        o1.x = packbf(alpha * ar1[0], alpha * ai1[0]);
        o1.y = packbf(alpha * ar1[1], alpha * ai1[1]);
        o1.z = packbf(alpha * ar1[2], alpha * ai1[2]);
        o1.w = packbf(alpha * ar1[3], alpha * ai1[3]);
        *(uint4*)(Bpl + (size_t)(kd0 * 10 + lt) * 2560 + pt0 * 256 + lane * 4) = o0;
        *(uint4*)(Bpl + (size_t)(kd1 * 10 + lt) * 2560 + pt1 * 256 + lane * 4) = o1;
    }
}

// ---------------------------------------------------------------------------
// Stage 2: T[j][l][kd] = sum_p W[j][p]*B[kd][p][l].
// Block = (kd-octet, l-tile, plane), 640 thr = 10 waves = 10 j-tiles.
// B octet staged once into 80KB LDS; W A-frags register-hoisted.
// ---------------------------------------------------------------------------
__global__ __launch_bounds__(640) void k_stage2(
    const unsigned int* __restrict__ Bfrag,
    const unsigned short* __restrict__ Wre,
    unsigned int* __restrict__ Tall)
{
    __shared__ __align__(16) unsigned int sB[20480];   // 80 KB: 8 kd x 2560
    int tid = threadIdx.x;
    int w = tid >> 6, lane = tid & 63;
    int col = lane & 15, g4 = lane >> 4;
    int kdo = blockIdx.x;
    int lt  = blockIdx.y;
    int plane = blockIdx.z;

    const unsigned int* Bp = Bfrag + (size_t)plane * PLANE_U;
    #pragma unroll
    for (int i = 0; i < 8; i++) {
        uint4 v = *(const uint4*)(Bp + ((size_t)(kdo * 8 + i) * 10 + lt) * 2560 + tid * 4);
        *(uint4*)(sB + i * 2560 + tid * 4) = v;
    }

    bf16x8 wfr[10];
    const unsigned short* wp = &Wre[(w * 16 + col) * KP + g4 * 8];
    #pragma unroll
    for (int t = 0; t < 10; t++)
        wfr[t] = *(const bf16x8*)(wp + t * 32);

    __syncthreads();

    f32x4 ar[8], ai[8];
    #pragma unroll
    for (int i = 0; i < 8; i++) { ar[i] = (f32x4)(0.f); ai[i] = (f32x4)(0.f); }

    #pragma unroll
    for (int t = 0; t < 10; t++) {
        union { bf16x8 b; uint4 u; } cr, ci;
        cr.b = wfr[t];
        ci.u.x = wim_of(cr.u.x); ci.u.y = wim_of(cr.u.y);
        ci.u.z = wim_of(cr.u.z); ci.u.w = wim_of(cr.u.w);
        #pragma unroll
        for (int kq = 0; kq < 8; kq++) {
            bf16x8 bf = *(const bf16x8*)&sB[kq * 2560 + (t * 64 + lane) * 4];
            ar[kq] = __builtin_amdgcn_mfma_f32_16x16x32_bf16(cr.b, bf, ar[kq], 0, 0, 0);
            ai[kq] = __builtin_amdgcn_mfma_f32_16x16x32_bf16(ci.b, bf, ai[kq], 0, 0, 0);
        }
    }

    unsigned int* Tp = Tall + (size_t)plane * PLANE_U;
    #pragma unroll
    for (int reg = 0; reg < 4; reg++) {
        int j = w * 16 + g4 * 4 + reg;
        int l = lt * 16 + col;
        uint4 o0, o1;
        o0.x = packbf(ar[0][reg], ai[0][reg]);
        o0.y = packbf(ar[1][reg], ai[1][reg]);
        o0.z = packbf(ar[2][reg], ai[2][reg]);
        o0.w = packbf(ar[3][reg], ai[3][reg]);
        o1.x = packbf(ar[4][reg], ai[4][reg]);
        o1.y = packbf(ar[5][reg], ai[5][reg]);
        o1.z = packbf(ar[6][reg], ai[6][reg]);
        o1.w = packbf(ar[7][reg], ai[7][reg]);
        size_t ta = ((size_t)(j * G + l)) * KD + kdo * 8;
        *(uint4*)(Tp + ta)     = o0;
        *(uint4*)(Tp + ta + 4) = o1;
    }
}

// ---------------------------------------------------------------------------
// Sampler: 16 lanes/point, lane = k. Phase-split for MLP: compute all 3
// planes' addresses+weights, issue all 24 uint4 loads, then do the math.
// ---------------------------------------------------------------------------
__device__ __forceinline__ void plane_addr(const unsigned int* __restrict__ T,
    float gy, float gx, int k, const unsigned int** cp, float* wv)
{
    float iy = (gy + 1.0f) * (0.5f * (float)GM1);
    float ix = (gx + 1.0f) * (0.5f * (float)GM1);
    float iy0f = floorf(iy), ix0f = floorf(ix);
    float wy = iy - iy0f, wx = ix - ix0f;
    int iy0 = (int)iy0f, ix0 = (int)ix0f;
    int iy1 = min(iy0 + 1, GM1), ix1 = min(ix0 + 1, GM1);
    iy0 = max(min(iy0, GM1), 0); ix0 = max(min(ix0, GM1), 0);
    iy1 = max(iy1, 0); ix1 = max(ix1, 0);
    cp[0] = &T[(size_t)(iy0 * G + ix0) * KD + k * 8];
    cp[1] = &T[(size_t)(iy0 * G + ix1) * KD + k * 8];
    cp[2] = &T[(size_t)(iy1 * G + ix0) * KD + k * 8];
    cp[3] = &T[(size_t)(iy1 * G + ix1) * KD + k * 8];
    wv[0] = (1.f - wx) * (1.f - wy);
    wv[1] = wx * (1.f - wy);
    wv[2] = (1.f - wx) * wy;
    wv[3] = wx * wy;
}

__device__ __forceinline__ float plane_math(const uint4* va, const uint4* vb,
                                            const float* wv, float fc)
{
    float w00 = wv[0], w01 = wv[1], w10 = wv[2], w11 = wv[3];
    float s1v, c1v;
    __sincosf(TWO_PI_F * fc, &s1v, &c1v);
    float cd[8], sd[8];
    cd[1] = c1v; sd[1] = s1v;
    #pragma unroll
    for (int d = 2; d < 8; d++) {
        float t2 = cd[d - 1] + cd[d - 1];
        cd[d] = __builtin_fmaf(t2, cd[d - 1], -1.0f);
        sd[d] = t2 * sd[d - 1];
    }
    float acc = 0.f;
#define TERM(u0, u1, u2, u3, C, S) { \
    float re = bfl(u0) * w00 + bfl(u1) * w01 + bfl(u2) * w10 + bfl(u3) * w11; \
    float im = bfh(u0) * w00 + bfh(u1) * w01 + bfh(u2) * w10 + bfh(u3) * w11; \
    acc += re * (C) - im * (S); }
    TERM(va[0].x, va[1].x, va[2].x, va[3].x, 1.0f, 0.0f)
    TERM(va[0].y, va[1].y, va[2].y, va[3].y, cd[1] + cd[1], sd[1] + sd[1])
    TERM(va[0].z, va[1].z, va[2].z, va[3].z, cd[2] + cd[2], sd[2] + sd[2])
    TERM(va[0].w, va[1].w, va[2].w, va[3].w, cd[3] + cd[3], sd[3] + sd[3])
    TERM(vb[0].x, vb[1].x, vb[2].x, vb[3].x, cd[4] + cd[4], sd[4] + sd[4])
    TERM(vb[0].y, vb[1].y, vb[2].y, vb[3].y, cd[5] + cd[5], sd[5] + sd[5])
    TERM(vb[0].z, vb[1].z, vb[2].z, vb[3].z, cd[6] + cd[6], sd[6] + sd[6])
    TERM(vb[0].w, vb[1].w, vb[2].w, vb[3].w, cd[7] + cd[7], sd[7] + sd[7])
#undef TERM
    return acc;
}

__global__ __launch_bounds__(256, 3) void k_sample(
    const float4* __restrict__ sxyz,
    const unsigned int* __restrict__ Tu, const unsigned int* __restrict__ Tv,
    const unsigned int* __restrict__ Tw,
    float* __restrict__ out, int N)
{
    int tid = threadIdx.x;
    int k = tid & 15;
    int nblocks = (N + 15) / 16;
    int seg = blockIdx.x & 7;
    int segblocks = nblocks >> 3;                 // N multiple of 128
    int pid = (seg * segblocks + (blockIdx.x >> 3)) * 16 + (tid >> 4);
    if (pid >= N) return;

    float4 pw = sxyz[pid];
    int n = __float_as_int(pw.w);
    float x = pw.x, y = pw.y, z = pw.z;

    const unsigned int* cp[3][4];
    float wv[3][4];
    plane_addr(Tu, y, z, k, cp[0], wv[0]);
    plane_addr(Tv, x, z, k, cp[1], wv[1]);
    plane_addr(Tw, y, x, k, cp[2], wv[2]);

    uint4 va[3][4], vb[3][4];
    #pragma unroll
    for (int pl = 0; pl < 3; pl++)
        #pragma unroll
        for (int c = 0; c < 4; c++) {
            va[pl][c] = *(const uint4*)cp[pl][c];
            vb[pl][c] = *(const uint4*)(cp[pl][c] + 4);
        }

    float acc = plane_math(va[0], vb[0], wv[0], (x + 1.0f) * 0.5f)
              + plane_math(va[1], vb[1], wv[1], (y + 1.0f) * 0.5f)
              + plane_math(va[2], vb[2], wv[2], (z + 1.0f) * 0.5f);
    out[n * 16 + k] = acc;
}

// ---------------------------------------------------------------------------
extern "C" void kernel_launch(void* const* d_in, const int* in_sizes, int n_in,
                              void* d_out, int out_size, void* d_ws, size_t ws_size,
                              hipStream_t stream) {
    const float* xyz          = (const float*)d_in[0];
    const float* bound        = (const float*)d_in[1];
    const float* alpha_params = (const float*)d_in[2];
    const float* Pu_re = (const float*)d_in[3];
    const float* Pu_im = (const float*)d_in[4];
    const float* Pv_re = (const float*)d_in[5];
    const float* Pv_im = (const float*)d_in[6];
    const float* Pw_re = (const float*)d_in[7];
    const float* Pw_im = (const float*)d_in[8];
    float* out = (float*)d_out;
    int N = in_sizes[0] / 3;

    // ws: Wre 100K | Apw 12.5M | Bfrag 37.5M | T 37.5M | counts 16K |
    //     cursors 16K | sxyz 2M
    char* ws = (char*)d_ws;
    unsigned short* Wre  = (unsigned short*)(ws);
    unsigned int*   Apw  = (unsigned int*)(ws + 102400);
    unsigned int*   Bfr  = (unsigned int*)(ws + 102400 + 13107200);
    unsigned int*   Tall = (unsigned int*)(ws + 102400 + 13107200 + 39321600);
    char*           ws2  = ws + 102400 + 13107200 + 39321600 + 39321600;
    unsigned int*   counts  = (unsigned int*)(ws2);
    unsigned int*   cursors = (unsigned int*)(ws2 + 16384);
    float4*         sxyz    = (float4*)(ws2 + 32768);
    unsigned int*   Tu   = Tall;
    unsigned int*   Tv   = Tall + (size_t)PLANE_U;
    unsigned int*   Tw   = Tall + (size_t)2 * PLANE_U;

    // fused prep: zero counts + W table + Pw pack
    k_prep<<<1816, 256, 0, stream>>>(Pw_re, Pw_im, Apw, Wre, counts);
    // sort chain
    k_hist<<<(N + 255) / 256, 256, 0, stream>>>(xyz, bound, counts, N);
    k_scan<<<1, 1024, 0, stream>>>(counts, cursors);
    k_scatter<<<(N + 255) / 256, 256, 0, stream>>>(xyz, bound, cursors, sxyz, N);
    // DFT pipeline
    k_stage1<<<240, 512, 0, stream>>>(Pu_re, Pu_im, Pv_re, Pv_im, Apw,
                                      alpha_params, Wre, Bfr);
    k_stage2<<<dim3(16, 10, 3), 640, 0, stream>>>(Bfr, Wre, Tall);
    // sampler
    k_sample<<<(N + 15) / 16, 256, 0, stream>>>(sxyz, Tu, Tv, Tw, out, N);
}